// Round 13
// baseline (521.562 us; speedup 1.0000x reference)
//
#include <hip/hip_runtime.h>
#include <hip/hip_bf16.h>

#define N_NODES 100000
#define N_EDGES 3200000
#define N_GRAPHS 512
#define IN_DIM 29
#define HID 128
#define LAT 256
#define NB 391     // ceil(N_NODES/256) dst-buckets
#define CAP 9216   // per-bucket packed capacity (mean 8184, sigma~90 -> +11 sigma)

typedef unsigned int uint;
typedef unsigned short ushort;
typedef float v4f __attribute__((ext_vector_type(4)));
typedef short v8s __attribute__((ext_vector_type(8)));

// round-to-nearest-even fp32 -> bf16 (finite inputs)
__device__ __forceinline__ ushort f2bf(float f) {
    uint u = __float_as_uint(f);
    return (ushort)((u + 0x7FFFu + ((u >> 16) & 1u)) >> 16);
}
__device__ __forceinline__ float bf2f(ushort h) { return __uint_as_float(((uint)h) << 16); }
__device__ __forceinline__ float bf_lo(uint p) { return __uint_as_float(p << 16); }
__device__ __forceinline__ float bf_hi(uint p) { return __uint_as_float(p & 0xFFFF0000u); }
__device__ __forceinline__ uint pack2(float a, float b) {
    return (uint)f2bf(a) | ((uint)f2bf(b) << 16);
}

__device__ __forceinline__ void bfadd(float* a, uint4 q) {
    a[0] += bf_lo(q.x); a[1] += bf_hi(q.x);
    a[2] += bf_lo(q.y); a[3] += bf_hi(q.y);
    a[4] += bf_lo(q.z); a[5] += bf_hi(q.z);
    a[6] += bf_lo(q.w); a[7] += bf_hi(q.w);
}

// ---------------- preprocessing ----------------

// Single-pass binning. R24: 256-thread blocks x 2048 edges (grid 1563) —
// binA was one of the two ~85-90us invisible kernels; with only 391 fat
// blocks it was serialization/LDS-atomic-contention-bound (traffic floor
// ~12us). 4x more blocks = better CU overlap + 4x fewer waves per histogram.
// bin by dst>>8 into fixed-stride CAP regions. pack (dst&255)<<17 | src.
__global__ __launch_bounds__(256, 4) void k_binA(const int* __restrict__ src, const int* __restrict__ dst,
                                                 int* __restrict__ bktCnt, int* __restrict__ packed, int e) {
    __shared__ int hist[NB];
    __shared__ int base[NB];
    int t = threadIdx.x;
    for (int i = t; i < NB; i += 256) hist[i] = 0;
    __syncthreads();
    int d[8], s[8];
    const int blockStart = blockIdx.x * 2048;
    #pragma unroll
    for (int k = 0; k < 8; ++k) {
        int idx = blockStart + k * 256 + t;
        if (idx < e) {
            d[k] = dst[idx];
            s[k] = src[idx];
            atomicAdd(&hist[d[k] >> 8], 1);
        } else d[k] = -1;
    }
    __syncthreads();
    for (int i = t; i < NB; i += 256) {
        int c = hist[i];
        base[i] = c ? atomicAdd(&bktCnt[i], c) : 0;   // bucket-local offset
    }
    __syncthreads();
    #pragma unroll
    for (int k = 0; k < 8; ++k) {
        if (d[k] >= 0) {
            int b = d[k] >> 8;
            int pos = atomicAdd(&base[b], 1);
            if (pos < CAP) packed[b * CAP + pos] = ((d[k] & 255) << 17) | s[k];
        }
    }
}

// Phase B: per bucket, 1024 threads. R22: k_bscan folded in — each block
// computes its own colBase = sum_{i<b} min(bktCnt[i],CAP) (391 L2 reads +
// block reduce, fully parallel) instead of a serial 1-block scan launch.
// Then: count per-(node, src-segment) keys (seg = src>>12, 25 live segments,
// padded 32), scan the 8192 keys -> rp & dis + per-key cursors, scatter col
// grouped by (node, seg) seg-ascending for k_agg gather locality.
// R19: k_scale fused — also writes xt[node][0:32] = dis*x[node][0:29].
__global__ __launch_bounds__(1024, 2) void k_binB(const int* __restrict__ bktCnt,
                                                  const int* __restrict__ packed, int* __restrict__ col,
                                                  int* __restrict__ rp, float* __restrict__ dis,
                                                  const float* __restrict__ x, float* __restrict__ xt, int n) {
    __shared__ int cnt[8192];     // 32 KB: per-(node,seg) counts -> cursors
    __shared__ int sh[1024];      // 4 KB: block scan / reduce buffer
    __shared__ float sdis[256];   // 1 KB: dis for this bucket's nodes
    const int b = blockIdx.x;
    int cntB = bktCnt[b];
    if (cntB > CAP) cntB = CAP;
    const int segS = b * CAP;
    int t = threadIdx.x;
    // folded bscan: prefix over buckets < b
    int part = 0;
    for (int i = t; i < b; i += 1024) {
        int c = bktCnt[i];
        part += (c > CAP) ? CAP : c;
    }
    #pragma unroll
    for (int k = 0; k < 8; ++k) cnt[t + k * 1024] = 0;
    sh[t] = part;
    __syncthreads();
    for (int off = 512; off > 0; off >>= 1) {
        if (t < off) sh[t] += sh[t + off];
        __syncthreads();
    }
    const int colBase = sh[0];
    // (sh reused below only after the counting barrier -> no extra sync needed)
    for (int j = t; j < cntB; j += 1024) {
        int pk = packed[segS + j];
        int key = ((pk >> 17) << 5) | ((pk & 0x1FFFF) >> 12);
        atomicAdd(&cnt[key], 1);
    }
    __syncthreads();
    // exclusive scan of cnt[8192]: thread t owns keys [8t, 8t+8)
    int base8 = t << 3;
    int v[8];
    int sum = 0;
    #pragma unroll
    for (int k = 0; k < 8; ++k) { v[k] = cnt[base8 + k]; sum += v[k]; }
    sh[t] = sum;
    __syncthreads();
    for (int off = 1; off < 1024; off <<= 1) {
        int x2 = (t >= off) ? sh[t - off] : 0;
        __syncthreads();
        sh[t] += x2;
        __syncthreads();
    }
    int run = colBase + sh[t] - sum;
    #pragma unroll
    for (int k = 0; k < 8; ++k) { cnt[base8 + k] = run; run += v[k]; }
    __syncthreads();
    if (t < 256) {
        int node = (b << 8) + t;
        int start = cnt[t << 5];
        int next = (t == 255) ? (colBase + cntB) : cnt[(t + 1) << 5];
        int deg = next - start;
        float dv = rsqrtf((float)deg + 1.0f);
        sdis[t] = dv;
        if (node <= n) rp[node] = start;      // node==n (last bucket) -> rp[n] = E
        if (node < n) dis[node] = dv;
    }
    __syncthreads();
    // fused x-tilde: xt[node][k] = dis[node]*x[node][k] (k<29), 0 pad to 32
    for (int idx = t; idx < 256 * 32; idx += 1024) {
        int loc = idx >> 5;
        int node = (b << 8) + loc;
        if (node < n) {
            int k = idx & 31;
            float vv = (k < IN_DIM) ? x[(size_t)node * IN_DIM + k] * sdis[loc] : 0.f;
            xt[((size_t)node << 5) + k] = vv;
        }
    }
    for (int j = t; j < cntB; j += 1024) {
        int pk = packed[segS + j];
        int key = ((pk >> 17) << 5) | ((pk & 0x1FFFF) >> 12);
        int pos = atomicAdd(&cnt[key], 1);
        col[pos] = pk & 0x1FFFF;
    }
}

// ---------------- W pack (all 3 layers) + zero bktCnt (runs first) ----------------
// layout index = ((kstep*8 + ntile)*64 + lane)*8 + j
// element = W[kstep*32 + (lane>>4)*8 + j][ntile*16 + (lane&15)]

__device__ __forceinline__ void pack_one(const float* W, ushort* hi, ushort* lo, int Ksrc, int idx) {
    int j = idx & 7;
    int lane = (idx >> 3) & 63;
    int nt = (idx >> 9) & 7;
    int ks = idx >> 12;
    int k = ks * 32 + (lane >> 4) * 8 + j;
    int n = nt * 16 + (lane & 15);
    float v = (k < Ksrc) ? W[k * 128 + n] : 0.f;
    ushort h = f2bf(v);
    ushort l = f2bf(v - bf2f(h));
    hi[idx] = h;
    lo[idx] = l;
}

__global__ __launch_bounds__(256) void k_pack_all(const float* __restrict__ W1, const float* __restrict__ W2,
                                                  const float* __restrict__ W3,
                                                  ushort* w1h, ushort* w1l, ushort* w2h, ushort* w2l,
                                                  ushort* w3h, ushort* w3l, int* __restrict__ bktCnt) {
    int idx = blockIdx.x * 256 + threadIdx.x;
    if (idx < NB) bktCnt[idx] = 0;        // fold the zeroing launch in here
    if (idx < 4096) {
        pack_one(W1, w1h, w1l, IN_DIM, idx);
    } else if (idx < 4096 + 16384) {
        pack_one(W2, w2h, w2l, HID, idx - 4096);
    } else if (idx < 4096 + 32768) {
        pack_one(W3, w3h, w3l, HID, idx - 4096 - 16384);
    }
}

// ---------------- layer 1 fused: 29-dim agg + GEMM + bias + relu (R22) ----------------
// Block = 256 threads = 32 consecutive nodes (N = 3125*32 exactly).
// Phase 1 (agg): 8 lanes/node, 4 floats/lane, 8-deep gather (R12 showed
// 4-deep+(256,8) raises occupancy AND FETCH — net loss; keep R11 config);
// y-row -> LDS [32][36] fp32. Phase 2 (gemm): 4 waves, wave w: m-tile (w>>1),
// nt range (w&1)*4..+4; split-precision Yhi@Whi + Yhi@Wlo + Ylo@Whi;
// bias+relu epilogue. y never touches HBM.

__global__ __launch_bounds__(256, 6) void k_l1(const float* __restrict__ xt, const int* __restrict__ rp,
                                               const int* __restrict__ col, const float* __restrict__ dis,
                                               const ushort* __restrict__ Whi, const ushort* __restrict__ Wlo,
                                               const float* __restrict__ bias, ushort* __restrict__ out, int n) {
    __shared__ float yl[32][36];
    int t = threadIdx.x;
    int loc = t >> 3;
    int node = blockIdx.x * 32 + loc;
    int c4 = (t & 7) << 2;
    if (node < n) {
        int s = rp[node], e = rp[node + 1];
        v4f A = (v4f){0.f, 0.f, 0.f, 0.f};
        v4f B = (v4f){0.f, 0.f, 0.f, 0.f};
        int j = s;
        for (; j + 7 < e; j += 8) {
            int c0 = col[j],     c1 = col[j + 1], c2 = col[j + 2], c3 = col[j + 3];
            int c4i = col[j + 4], c5 = col[j + 5], c6 = col[j + 6], c7 = col[j + 7];
            v4f q0 = *(const v4f*)(xt + ((size_t)c0 << 5) + c4);
            v4f q1 = *(const v4f*)(xt + ((size_t)c1 << 5) + c4);
            v4f q2 = *(const v4f*)(xt + ((size_t)c2 << 5) + c4);
            v4f q3 = *(const v4f*)(xt + ((size_t)c3 << 5) + c4);
            v4f q4 = *(const v4f*)(xt + ((size_t)c4i << 5) + c4);
            v4f q5 = *(const v4f*)(xt + ((size_t)c5 << 5) + c4);
            v4f q6 = *(const v4f*)(xt + ((size_t)c6 << 5) + c4);
            v4f q7 = *(const v4f*)(xt + ((size_t)c7 << 5) + c4);
            A += q0; B += q1; A += q2; B += q3;
            A += q4; B += q5; A += q6; B += q7;
        }
        if (j + 3 < e) {
            int c0 = col[j], c1 = col[j + 1], c2 = col[j + 2], c3 = col[j + 3];
            v4f q0 = *(const v4f*)(xt + ((size_t)c0 << 5) + c4);
            v4f q1 = *(const v4f*)(xt + ((size_t)c1 << 5) + c4);
            v4f q2 = *(const v4f*)(xt + ((size_t)c2 << 5) + c4);
            v4f q3 = *(const v4f*)(xt + ((size_t)c3 << 5) + c4);
            A += q0; B += q1; A += q2; B += q3;
            j += 4;
        }
        for (; j < e; ++j) {
            int c = col[j];
            A += *(const v4f*)(xt + ((size_t)c << 5) + c4);
        }
        A += *(const v4f*)(xt + ((size_t)node << 5) + c4);
        float dv = dis[node];
        v4f o = (A + B) * dv;
        yl[loc][c4 + 0] = o.x;
        yl[loc][c4 + 1] = o.y;
        yl[loc][c4 + 2] = o.z;
        yl[loc][c4 + 3] = o.w;
    }
    __syncthreads();
    // gemm phase
    const int wave = t >> 6;
    const int lane = t & 63;
    const int mrow = ((wave >> 1) << 4) + (lane & 15);   // local row 0..31
    const int ntBase = (wave & 1) * 4;
    const int kh = (lane >> 4) * 8;
    float a[8];
    #pragma unroll
    for (int j = 0; j < 8; ++j) a[j] = yl[mrow][kh + j];
    v8s ahi, alo;
    #pragma unroll
    for (int j = 0; j < 8; ++j) {
        ushort h = f2bf(a[j]);
        ushort l = f2bf(a[j] - bf2f(h));
        ahi[j] = (short)h;
        alo[j] = (short)l;
    }
    const ushort* bh = Whi + (size_t)lane * 8;
    const ushort* bl = Wlo + (size_t)lane * 8;
    v4f acc[4];
    #pragma unroll
    for (int i = 0; i < 4; ++i) acc[i] = (v4f){0.f, 0.f, 0.f, 0.f};
    #pragma unroll
    for (int i = 0; i < 4; ++i) {
        int nt = ntBase + i;
        v8s bhi = *(const v8s*)(bh + nt * 512);
        v8s blo = *(const v8s*)(bl + nt * 512);
        acc[i] = __builtin_amdgcn_mfma_f32_16x16x32_bf16(ahi, bhi, acc[i], 0, 0, 0);
        acc[i] = __builtin_amdgcn_mfma_f32_16x16x32_bf16(ahi, blo, acc[i], 0, 0, 0);
        acc[i] = __builtin_amdgcn_mfma_f32_16x16x32_bf16(alo, bhi, acc[i], 0, 0, 0);
    }
    const int col0 = lane & 15;
    const int orow0 = blockIdx.x * 32 + ((wave >> 1) << 4) + ((lane >> 4) << 2);
    float bb[4];
    #pragma unroll
    for (int i = 0; i < 4; ++i) bb[i] = bias[(ntBase + i) * 16 + col0];
    #pragma unroll
    for (int r = 0; r < 4; ++r) {
        int orow = orow0 + r;
        if (orow < n) {
            #pragma unroll
            for (int i = 0; i < 4; ++i)
                out[(size_t)orow * 128 + (ntBase + i) * 16 + col0] = f2bf(fmaxf(acc[i][r] + bb[i], 0.f));
        }
    }
}

// ---------------- MFMA GEMM (layers 2,3): hws = dis * (h_bf16 @ W) ----------------
// R19: 32 rows/wave (2 m-tiles share each weight-fragment load). bounds (256,4).
// Stores CACHED: A-writes warm L2 for the following k_agg gather.

__global__ __launch_bounds__(256, 4) void k_gemm_bf32(const ushort* __restrict__ in,
                                                      const ushort* __restrict__ Whi,
                                                      const ushort* __restrict__ Wlo,
                                                      const float* __restrict__ dis,
                                                      ushort* __restrict__ out, int n) {
    const int wave = threadIdx.x >> 6;
    const int lane = threadIdx.x & 63;
    const int m0 = (blockIdx.x * 4 + wave) * 32;
    if (m0 >= n) return;
    int row0 = m0 + (lane & 15);
    int row1 = row0 + 16;
    if (row0 >= n) row0 = n - 1;
    if (row1 >= n) row1 = n - 1;
    const int kh = (lane >> 4) * 8;
    const ushort* rp0 = in + (size_t)row0 * 128 + kh;
    const ushort* rp1 = in + (size_t)row1 * 128 + kh;

    v4f acc0[8], acc1[8];
    #pragma unroll
    for (int t = 0; t < 8; ++t) {
        acc0[t] = (v4f){0.f, 0.f, 0.f, 0.f};
        acc1[t] = (v4f){0.f, 0.f, 0.f, 0.f};
    }

    #pragma unroll
    for (int ks = 0; ks < 4; ++ks) {
        v8s a0 = *(const v8s*)(rp0 + ks * 32);
        v8s a1 = *(const v8s*)(rp1 + ks * 32);
        const ushort* bh = Whi + (size_t)(ks * 8) * 512 + (size_t)lane * 8;
        const ushort* bl = Wlo + (size_t)(ks * 8) * 512 + (size_t)lane * 8;
        #pragma unroll
        for (int nt = 0; nt < 8; ++nt) {
            v8s bhi = *(const v8s*)(bh + nt * 512);
            v8s blo = *(const v8s*)(bl + nt * 512);
            acc0[nt] = __builtin_amdgcn_mfma_f32_16x16x32_bf16(a0, bhi, acc0[nt], 0, 0, 0);
            acc0[nt] = __builtin_amdgcn_mfma_f32_16x16x32_bf16(a0, blo, acc0[nt], 0, 0, 0);
            acc1[nt] = __builtin_amdgcn_mfma_f32_16x16x32_bf16(a1, bhi, acc1[nt], 0, 0, 0);
            acc1[nt] = __builtin_amdgcn_mfma_f32_16x16x32_bf16(a1, blo, acc1[nt], 0, 0, 0);
        }
    }

    const int col0 = lane & 15;
    const int orow0 = m0 + (lane >> 4) * 4;
    #pragma unroll
    for (int r = 0; r < 4; ++r) {
        int orow = orow0 + r;
        if (orow < n) {
            float dv = dis[orow];
            #pragma unroll
            for (int nt = 0; nt < 8; ++nt)
                out[(size_t)orow * 128 + nt * 16 + col0] = f2bf(acc0[nt][r] * dv);
        }
        int orow2 = orow + 16;
        if (orow2 < n) {
            float dv = dis[orow2];
            #pragma unroll
            for (int nt = 0; nt < 8; ++nt)
                out[(size_t)orow2 * 128 + nt * 16 + col0] = f2bf(acc1[nt][r] * dv);
        }
    }
}

// ---------------- aggregation (layers 2,3): channel-split, merged halves ----------------
// out[i][:] = bf16( relu( dis[i]*( sum_j hws[col[j]] + hws[i] ) + b ) )
// R16/R20: one 128-B line per edge per half; both halves in ONE dispatch.
// R12 lesson: occupancy and FETCH trade off (4-deep/(256,8): 76% occ, 3.64
// TB/s fill, but 318 MB FETCH -> 96.5us net loss). This 8-deep/(256,6)
// config (94.2us / 297 MB / 3.45 TB/s) is the measured local optimum.

__global__ __launch_bounds__(256, 6) void k_agg(const ushort* __restrict__ hws, const int* __restrict__ rp,
                                                const int* __restrict__ col, const float* __restrict__ dis,
                                                const float* __restrict__ bias, ushort* __restrict__ out, int n) {
    int g = blockIdx.x * 32 + (threadIdx.x >> 3);   // group id in [0, 2n)
    int node = (g < n) ? g : g - n;                 // half0: ch 0-63, half1: ch 64-127
    if (g >= 2 * n) return;
    int c8 = ((g < n) ? 0 : 64) + ((threadIdx.x & 7) << 3);
    int s = rp[node], e = rp[node + 1];
    float A[8] = {0.f, 0.f, 0.f, 0.f, 0.f, 0.f, 0.f, 0.f};
    float B[8] = {0.f, 0.f, 0.f, 0.f, 0.f, 0.f, 0.f, 0.f};
    int j = s;
    for (; j + 7 < e; j += 8) {
        int c0 = col[j],     c1 = col[j + 1], c2 = col[j + 2], c3 = col[j + 3];
        int c4 = col[j + 4], c5 = col[j + 5], c6 = col[j + 6], c7 = col[j + 7];
        uint4 q0 = *(const uint4*)(hws + ((size_t)c0 << 7) + c8);
        uint4 q1 = *(const uint4*)(hws + ((size_t)c1 << 7) + c8);
        uint4 q2 = *(const uint4*)(hws + ((size_t)c2 << 7) + c8);
        uint4 q3 = *(const uint4*)(hws + ((size_t)c3 << 7) + c8);
        uint4 q4 = *(const uint4*)(hws + ((size_t)c4 << 7) + c8);
        uint4 q5 = *(const uint4*)(hws + ((size_t)c5 << 7) + c8);
        uint4 q6 = *(const uint4*)(hws + ((size_t)c6 << 7) + c8);
        uint4 q7 = *(const uint4*)(hws + ((size_t)c7 << 7) + c8);
        bfadd(A, q0); bfadd(B, q1); bfadd(A, q2); bfadd(B, q3);
        bfadd(A, q4); bfadd(B, q5); bfadd(A, q6); bfadd(B, q7);
    }
    if (j + 3 < e) {
        int c0 = col[j], c1 = col[j + 1], c2 = col[j + 2], c3 = col[j + 3];
        uint4 q0 = *(const uint4*)(hws + ((size_t)c0 << 7) + c8);
        uint4 q1 = *(const uint4*)(hws + ((size_t)c1 << 7) + c8);
        uint4 q2 = *(const uint4*)(hws + ((size_t)c2 << 7) + c8);
        uint4 q3 = *(const uint4*)(hws + ((size_t)c3 << 7) + c8);
        bfadd(A, q0); bfadd(B, q1); bfadd(A, q2); bfadd(B, q3);
        j += 4;
    }
    for (; j < e; ++j) {
        int c = col[j];
        uint4 q = *(const uint4*)(hws + ((size_t)c << 7) + c8);
        bfadd(A, q);
    }
    uint4 qs = *(const uint4*)(hws + ((size_t)node << 7) + c8);
    bfadd(A, qs);
    float dv = dis[node];
    float4 bv0 = *(const float4*)(bias + c8);
    float4 bv1 = *(const float4*)(bias + c8 + 4);
    float r0 = fmaxf(dv * (A[0] + B[0]) + bv0.x, 0.f);
    float r1 = fmaxf(dv * (A[1] + B[1]) + bv0.y, 0.f);
    float r2 = fmaxf(dv * (A[2] + B[2]) + bv0.z, 0.f);
    float r3 = fmaxf(dv * (A[3] + B[3]) + bv0.w, 0.f);
    float r4 = fmaxf(dv * (A[4] + B[4]) + bv1.x, 0.f);
    float r5 = fmaxf(dv * (A[5] + B[5]) + bv1.y, 0.f);
    float r6 = fmaxf(dv * (A[6] + B[6]) + bv1.z, 0.f);
    float r7 = fmaxf(dv * (A[7] + B[7]) + bv1.w, 0.f);
    uint4 o;
    o.x = pack2(r0, r1);
    o.y = pack2(r2, r3);
    o.z = pack2(r4, r5);
    o.w = pack2(r6, r7);
    *(uint4*)(out + (size_t)node * 128 + c8) = o;
}

// ---------------- fused mean-pool + heads (bf16 h input) ----------------

__global__ __launch_bounds__(256) void k_pool_head(const ushort* __restrict__ h, const int* __restrict__ batch,
                                                   const float* __restrict__ Wmu, const float* __restrict__ bmu,
                                                   const float* __restrict__ Wlv, const float* __restrict__ blv,
                                                   float* __restrict__ out, int n) {
    int g = blockIdx.x;
    int t = threadIdx.x;
    int lo = 0, hi = n;
    while (lo < hi) { int m = (lo + hi) >> 1; if (batch[m] < g) lo = m + 1; else hi = m; }
    int start = lo;
    hi = n;
    while (lo < hi) { int m = (lo + hi) >> 1; if (batch[m] < g + 1) lo = m + 1; else hi = m; }
    int end = lo;

    __shared__ float sh0[256];
    __shared__ float sh1[256];
    __shared__ float pooled[128];
    int lane = t & 63;
    int grp = t >> 6;
    float a0 = 0.f, a1 = 0.f;
    for (int i = start + grp; i < end; i += 4) {
        uint q = *(const uint*)(h + (size_t)i * 128 + lane * 2);
        a0 += bf_lo(q);
        a1 += bf_hi(q);
    }
    sh0[t] = a0;
    sh1[t] = a1;
    __syncthreads();
    if (t < 64) {
        float cnt = (float)(end - start);
        float inv = 1.0f / fmaxf(cnt, 1.0f);
        float s0 = sh0[t] + sh0[t + 64] + sh0[t + 128] + sh0[t + 192];
        float s1 = sh1[t] + sh1[t + 64] + sh1[t + 128] + sh1[t + 192];
        pooled[t * 2] = s0 * inv;
        pooled[t * 2 + 1] = s1 * inv;
    }
    __syncthreads();
    float amu = bmu[t], alv = blv[t];
    for (int k = 0; k < 128; k += 4) {
        float p0 = pooled[k], p1 = pooled[k + 1], p2 = pooled[k + 2], p3 = pooled[k + 3];
        amu += p0 * Wmu[(k + 0) * 256 + t] + p1 * Wmu[(k + 1) * 256 + t]
             + p2 * Wmu[(k + 2) * 256 + t] + p3 * Wmu[(k + 3) * 256 + t];
        alv += p0 * Wlv[(k + 0) * 256 + t] + p1 * Wlv[(k + 1) * 256 + t]
             + p2 * Wlv[(k + 2) * 256 + t] + p3 * Wlv[(k + 3) * 256 + t];
    }
    out[(size_t)g * 256 + t] = amu;
    out[(size_t)N_GRAPHS * 256 + (size_t)g * 256 + t] = alv;
}

// ---------------- launch ----------------

extern "C" void kernel_launch(void* const* d_in, const int* in_sizes, int n_in,
                              void* d_out, int out_size, void* d_ws, size_t ws_size,
                              hipStream_t stream) {
    const float* x    = (const float*)d_in[0];
    const int*   eidx = (const int*)d_in[1];
    const int*   batch= (const int*)d_in[2];
    const float* W1   = (const float*)d_in[3];
    const float* b1   = (const float*)d_in[4];
    const float* W2   = (const float*)d_in[5];
    const float* b2   = (const float*)d_in[6];
    const float* W3   = (const float*)d_in[7];
    const float* b3   = (const float*)d_in[8];
    const float* Wmu  = (const float*)d_in[9];
    const float* bmu  = (const float*)d_in[10];
    const float* Wlv  = (const float*)d_in[11];
    const float* blv  = (const float*)d_in[12];
    float* out = (float*)d_out;

    const int N = N_NODES, E = N_EDGES;
    const int* srcp = eidx;
    const int* dstp = eidx + E;

    // workspace layout
    ushort* w1h = (ushort*)d_ws;            // 4096
    ushort* w1l = w1h + 4096;               // 4096
    ushort* w2h = w1l + 4096;               // 16384
    ushort* w2l = w2h + 16384;              // 16384
    ushort* w3h = w2l + 16384;              // 16384
    ushort* w3l = w3h + 16384;              // 16384
    ushort* A   = w3l + 16384;              // N*128 bf16 (hws, gathered)
    ushort* B   = A + (size_t)N * 128;      // N*128 bf16 (h)
    float*  dis = (float*)(B + (size_t)N * 128);  // N
    int*   rp   = (int*)(dis + N);          // N+1 (pad 2)
    int*   bktCnt   = rp + (N + 2);         // NB (pad 512)
    int*   colStart = bktCnt + 512;         // NB+1 (pad 512) — unused since R22
    int*   packed = colStart + 512;         // NB*CAP
    int*   col    = packed + (size_t)NB * CAP;  // E

    // layer-1 fp32 table aliases A (dead until k_gemm_bf32 writes it):
    // xt = N*32 f32 (12.8 MB). y lives in LDS only (R22 fusion).
    float* xt = (float*)A;

    const int gE2048 = (E + 2047) / 2048;   // 1563

    // W packs + bktCnt zeroing (one launch, runs before binA)
    k_pack_all<<<144, 256, 0, stream>>>(W1, W2, W3, w1h, w1l, w2h, w2l, w3h, w3l, bktCnt);

    // single-pass binned CSR build; binB folds bscan + emits xt
    k_binA<<<gE2048, 256, 0, stream>>>(srcp, dstp, bktCnt, packed, E);
    k_binB<<<NB, 1024, 0, stream>>>(bktCnt, packed, col, rp, dis, x, xt, N);

    const int gGemm2 = (N + 127) / 128;     // 782  (32 rows/wave)
    const int gL1    = (N + 31) / 32;       // 3125 (32 nodes/block)
    const int gAgg   = (2 * N + 31) / 32;   // 6250: both halves, one dispatch

    // layer 1: fused 29-dim agg + GEMM(+bias+relu)
    k_l1<<<gL1, 256, 0, stream>>>(xt, rp, col, dis, w1h, w1l, b1, B, N);

    // layers 2,3: GEMM -> agg(+bias+relu), merged channel-halves
    k_gemm_bf32<<<gGemm2, 256, 0, stream>>>(B, w2h, w2l, dis, A, N);
    k_agg<<<gAgg, 256, 0, stream>>>(A, rp, col, dis, b2, B, N);
    k_gemm_bf32<<<gGemm2, 256, 0, stream>>>(B, w3h, w3l, dis, A, N);
    k_agg<<<gAgg, 256, 0, stream>>>(A, rp, col, dis, b3, B, N);
    k_pool_head<<<N_GRAPHS, 256, 0, stream>>>(B, batch, Wmu, bmu, Wlv, blv, out, N);
}

// Round 14
// 461.423 us; speedup vs baseline: 1.1303x; 1.1303x over previous
//
#include <hip/hip_runtime.h>
#include <hip/hip_bf16.h>

#define N_NODES 100000
#define N_EDGES 3200000
#define N_GRAPHS 512
#define IN_DIM 29
#define HID 128
#define LAT 256
#define NB 391     // ceil(N_NODES/256) dst-buckets
#define CAP 9216   // per-bucket packed capacity (mean 8184, sigma~90 -> +11 sigma)

typedef unsigned int uint;
typedef unsigned short ushort;
typedef float v4f __attribute__((ext_vector_type(4)));
typedef short v8s __attribute__((ext_vector_type(8)));

// round-to-nearest-even fp32 -> bf16 (finite inputs)
__device__ __forceinline__ ushort f2bf(float f) {
    uint u = __float_as_uint(f);
    return (ushort)((u + 0x7FFFu + ((u >> 16) & 1u)) >> 16);
}
__device__ __forceinline__ float bf2f(ushort h) { return __uint_as_float(((uint)h) << 16); }
__device__ __forceinline__ float bf_lo(uint p) { return __uint_as_float(p << 16); }
__device__ __forceinline__ float bf_hi(uint p) { return __uint_as_float(p & 0xFFFF0000u); }
__device__ __forceinline__ uint pack2(float a, float b) {
    return (uint)f2bf(a) | ((uint)f2bf(b) << 16);
}

__device__ __forceinline__ void bfadd(float* a, uint4 q) {
    a[0] += bf_lo(q.x); a[1] += bf_hi(q.x);
    a[2] += bf_lo(q.y); a[3] += bf_hi(q.y);
    a[4] += bf_lo(q.z); a[5] += bf_hi(q.z);
    a[6] += bf_lo(q.w); a[7] += bf_hi(q.w);
}

// ---------------- preprocessing ----------------

// Single-pass binning: 1024 threads x 8 edges = 8192 edges/block (R25: reverted
// to R11 config — R13's 256-thread blocks shrank per-bucket write runs 21->5
// edges, causing 7x write amplification (WRITE 89 MB vs 12.8 logical) and 96us
// vs 32us; fat blocks win BECAUSE of store combining). bin by dst>>8 into
// fixed-stride CAP regions. pack (dst&255)<<17 | src.
__global__ __launch_bounds__(1024, 2) void k_binA(const int* __restrict__ src, const int* __restrict__ dst,
                                                  int* __restrict__ bktCnt, int* __restrict__ packed, int e) {
    __shared__ int hist[NB];
    __shared__ int base[NB];
    int t = threadIdx.x;
    for (int i = t; i < NB; i += 1024) hist[i] = 0;
    __syncthreads();
    int d[8], s[8];
    const int blockStart = blockIdx.x * 8192;
    #pragma unroll
    for (int k = 0; k < 8; ++k) {
        int idx = blockStart + k * 1024 + t;
        if (idx < e) {
            d[k] = dst[idx];
            s[k] = src[idx];
            atomicAdd(&hist[d[k] >> 8], 1);
        } else d[k] = -1;
    }
    __syncthreads();
    for (int i = t; i < NB; i += 1024) {
        int c = hist[i];
        base[i] = c ? atomicAdd(&bktCnt[i], c) : 0;   // bucket-local offset
    }
    __syncthreads();
    #pragma unroll
    for (int k = 0; k < 8; ++k) {
        if (d[k] >= 0) {
            int b = d[k] >> 8;
            int pos = atomicAdd(&base[b], 1);
            if (pos < CAP) packed[b * CAP + pos] = ((d[k] & 255) << 17) | s[k];
        }
    }
}

// Phase B: per bucket, 1024 threads. R22: k_bscan folded in (per-block prefix
// over bktCnt). R25: packed STAGED IN LDS during the count pass — the scatter
// pass previously re-read all ~8184 entries from global (L2-warm, ~200cyc) and
// recomputed keys; binB wall time ~ one block's serial chain (391 blocks ~1.5/CU,
// all concurrent), so removing a full global pass cuts the chain ~30-40%.
// LDS: cnt 32K + pkb 36K + sh 4K + sdis 1K = 73 KB (thread-limit still binds
// occupancy at 2 blocks/CU). R19: k_scale fused — also writes xt rows.
__global__ __launch_bounds__(1024, 2) void k_binB(const int* __restrict__ bktCnt,
                                                  const int* __restrict__ packed, int* __restrict__ col,
                                                  int* __restrict__ rp, float* __restrict__ dis,
                                                  const float* __restrict__ x, float* __restrict__ xt, int n) {
    __shared__ int cnt[8192];     // 32 KB: per-(node,seg) counts -> cursors
    __shared__ int pkb[CAP];      // 36 KB: staged packed entries (R25)
    __shared__ int sh[1024];      // 4 KB: block scan / reduce buffer
    __shared__ float sdis[256];   // 1 KB: dis for this bucket's nodes
    const int b = blockIdx.x;
    int cntB = bktCnt[b];
    if (cntB > CAP) cntB = CAP;
    const int segS = b * CAP;
    int t = threadIdx.x;
    // folded bscan: prefix over buckets < b
    int part = 0;
    for (int i = t; i < b; i += 1024) {
        int c = bktCnt[i];
        part += (c > CAP) ? CAP : c;
    }
    #pragma unroll
    for (int k = 0; k < 8; ++k) cnt[t + k * 1024] = 0;
    sh[t] = part;
    __syncthreads();
    for (int off = 512; off > 0; off >>= 1) {
        if (t < off) sh[t] += sh[t + off];
        __syncthreads();
    }
    const int colBase = sh[0];
    // (sh reused below only after the counting barrier -> no extra sync needed)
    for (int j = t; j < cntB; j += 1024) {
        int pk = packed[segS + j];
        pkb[j] = pk;
        int key = ((pk >> 17) << 5) | ((pk & 0x1FFFF) >> 12);
        atomicAdd(&cnt[key], 1);
    }
    __syncthreads();
    // exclusive scan of cnt[8192]: thread t owns keys [8t, 8t+8)
    int base8 = t << 3;
    int v[8];
    int sum = 0;
    #pragma unroll
    for (int k = 0; k < 8; ++k) { v[k] = cnt[base8 + k]; sum += v[k]; }
    sh[t] = sum;
    __syncthreads();
    for (int off = 1; off < 1024; off <<= 1) {
        int x2 = (t >= off) ? sh[t - off] : 0;
        __syncthreads();
        sh[t] += x2;
        __syncthreads();
    }
    int run = colBase + sh[t] - sum;
    #pragma unroll
    for (int k = 0; k < 8; ++k) { cnt[base8 + k] = run; run += v[k]; }
    __syncthreads();
    if (t < 256) {
        int node = (b << 8) + t;
        int start = cnt[t << 5];
        int next = (t == 255) ? (colBase + cntB) : cnt[(t + 1) << 5];
        int deg = next - start;
        float dv = rsqrtf((float)deg + 1.0f);
        sdis[t] = dv;
        if (node <= n) rp[node] = start;      // node==n (last bucket) -> rp[n] = E
        if (node < n) dis[node] = dv;
    }
    __syncthreads();
    // fused x-tilde: xt[node][k] = dis[node]*x[node][k] (k<29), 0 pad to 32
    for (int idx = t; idx < 256 * 32; idx += 1024) {
        int loc = idx >> 5;
        int node = (b << 8) + loc;
        if (node < n) {
            int k = idx & 31;
            float vv = (k < IN_DIM) ? x[(size_t)node * IN_DIM + k] * sdis[loc] : 0.f;
            xt[((size_t)node << 5) + k] = vv;
        }
    }
    for (int j = t; j < cntB; j += 1024) {
        int pk = pkb[j];
        int key = ((pk >> 17) << 5) | ((pk & 0x1FFFF) >> 12);
        int pos = atomicAdd(&cnt[key], 1);
        col[pos] = pk & 0x1FFFF;
    }
}

// ---------------- W pack (all 3 layers) + zero bktCnt (runs first) ----------------
// layout index = ((kstep*8 + ntile)*64 + lane)*8 + j
// element = W[kstep*32 + (lane>>4)*8 + j][ntile*16 + (lane&15)]

__device__ __forceinline__ void pack_one(const float* W, ushort* hi, ushort* lo, int Ksrc, int idx) {
    int j = idx & 7;
    int lane = (idx >> 3) & 63;
    int nt = (idx >> 9) & 7;
    int ks = idx >> 12;
    int k = ks * 32 + (lane >> 4) * 8 + j;
    int n = nt * 16 + (lane & 15);
    float v = (k < Ksrc) ? W[k * 128 + n] : 0.f;
    ushort h = f2bf(v);
    ushort l = f2bf(v - bf2f(h));
    hi[idx] = h;
    lo[idx] = l;
}

__global__ __launch_bounds__(256) void k_pack_all(const float* __restrict__ W1, const float* __restrict__ W2,
                                                  const float* __restrict__ W3,
                                                  ushort* w1h, ushort* w1l, ushort* w2h, ushort* w2l,
                                                  ushort* w3h, ushort* w3l, int* __restrict__ bktCnt) {
    int idx = blockIdx.x * 256 + threadIdx.x;
    if (idx < NB) bktCnt[idx] = 0;        // fold the zeroing launch in here
    if (idx < 4096) {
        pack_one(W1, w1h, w1l, IN_DIM, idx);
    } else if (idx < 4096 + 16384) {
        pack_one(W2, w2h, w2l, HID, idx - 4096);
    } else if (idx < 4096 + 32768) {
        pack_one(W3, w3h, w3l, HID, idx - 4096 - 16384);
    }
}

// ---------------- layer 1 fused: 29-dim agg + GEMM + bias + relu (R22) ----------------
// Block = 256 threads = 32 consecutive nodes (N = 3125*32 exactly).
// Phase 1 (agg): 8 lanes/node, 4 floats/lane, 8-deep gather; y-row -> LDS
// [32][36] fp32. Phase 2 (gemm): 4 waves, wave w: m-tile (w>>1), nt range
// (w&1)*4..+4; split-precision Yhi@Whi + Yhi@Wlo + Ylo@Whi; bias+relu
// epilogue. y never touches HBM.

__global__ __launch_bounds__(256, 6) void k_l1(const float* __restrict__ xt, const int* __restrict__ rp,
                                               const int* __restrict__ col, const float* __restrict__ dis,
                                               const ushort* __restrict__ Whi, const ushort* __restrict__ Wlo,
                                               const float* __restrict__ bias, ushort* __restrict__ out, int n) {
    __shared__ float yl[32][36];
    int t = threadIdx.x;
    int loc = t >> 3;
    int node = blockIdx.x * 32 + loc;
    int c4 = (t & 7) << 2;
    if (node < n) {
        int s = rp[node], e = rp[node + 1];
        v4f A = (v4f){0.f, 0.f, 0.f, 0.f};
        v4f B = (v4f){0.f, 0.f, 0.f, 0.f};
        int j = s;
        for (; j + 7 < e; j += 8) {
            int c0 = col[j],     c1 = col[j + 1], c2 = col[j + 2], c3 = col[j + 3];
            int c4i = col[j + 4], c5 = col[j + 5], c6 = col[j + 6], c7 = col[j + 7];
            v4f q0 = *(const v4f*)(xt + ((size_t)c0 << 5) + c4);
            v4f q1 = *(const v4f*)(xt + ((size_t)c1 << 5) + c4);
            v4f q2 = *(const v4f*)(xt + ((size_t)c2 << 5) + c4);
            v4f q3 = *(const v4f*)(xt + ((size_t)c3 << 5) + c4);
            v4f q4 = *(const v4f*)(xt + ((size_t)c4i << 5) + c4);
            v4f q5 = *(const v4f*)(xt + ((size_t)c5 << 5) + c4);
            v4f q6 = *(const v4f*)(xt + ((size_t)c6 << 5) + c4);
            v4f q7 = *(const v4f*)(xt + ((size_t)c7 << 5) + c4);
            A += q0; B += q1; A += q2; B += q3;
            A += q4; B += q5; A += q6; B += q7;
        }
        if (j + 3 < e) {
            int c0 = col[j], c1 = col[j + 1], c2 = col[j + 2], c3 = col[j + 3];
            v4f q0 = *(const v4f*)(xt + ((size_t)c0 << 5) + c4);
            v4f q1 = *(const v4f*)(xt + ((size_t)c1 << 5) + c4);
            v4f q2 = *(const v4f*)(xt + ((size_t)c2 << 5) + c4);
            v4f q3 = *(const v4f*)(xt + ((size_t)c3 << 5) + c4);
            A += q0; B += q1; A += q2; B += q3;
            j += 4;
        }
        for (; j < e; ++j) {
            int c = col[j];
            A += *(const v4f*)(xt + ((size_t)c << 5) + c4);
        }
        A += *(const v4f*)(xt + ((size_t)node << 5) + c4);
        float dv = dis[node];
        v4f o = (A + B) * dv;
        yl[loc][c4 + 0] = o.x;
        yl[loc][c4 + 1] = o.y;
        yl[loc][c4 + 2] = o.z;
        yl[loc][c4 + 3] = o.w;
    }
    __syncthreads();
    // gemm phase
    const int wave = t >> 6;
    const int lane = t & 63;
    const int mrow = ((wave >> 1) << 4) + (lane & 15);   // local row 0..31
    const int ntBase = (wave & 1) * 4;
    const int kh = (lane >> 4) * 8;
    float a[8];
    #pragma unroll
    for (int j = 0; j < 8; ++j) a[j] = yl[mrow][kh + j];
    v8s ahi, alo;
    #pragma unroll
    for (int j = 0; j < 8; ++j) {
        ushort h = f2bf(a[j]);
        ushort l = f2bf(a[j] - bf2f(h));
        ahi[j] = (short)h;
        alo[j] = (short)l;
    }
    const ushort* bh = Whi + (size_t)lane * 8;
    const ushort* bl = Wlo + (size_t)lane * 8;
    v4f acc[4];
    #pragma unroll
    for (int i = 0; i < 4; ++i) acc[i] = (v4f){0.f, 0.f, 0.f, 0.f};
    #pragma unroll
    for (int i = 0; i < 4; ++i) {
        int nt = ntBase + i;
        v8s bhi = *(const v8s*)(bh + nt * 512);
        v8s blo = *(const v8s*)(bl + nt * 512);
        acc[i] = __builtin_amdgcn_mfma_f32_16x16x32_bf16(ahi, bhi, acc[i], 0, 0, 0);
        acc[i] = __builtin_amdgcn_mfma_f32_16x16x32_bf16(ahi, blo, acc[i], 0, 0, 0);
        acc[i] = __builtin_amdgcn_mfma_f32_16x16x32_bf16(alo, bhi, acc[i], 0, 0, 0);
    }
    const int col0 = lane & 15;
    const int orow0 = blockIdx.x * 32 + ((wave >> 1) << 4) + ((lane >> 4) << 2);
    float bb[4];
    #pragma unroll
    for (int i = 0; i < 4; ++i) bb[i] = bias[(ntBase + i) * 16 + col0];
    #pragma unroll
    for (int r = 0; r < 4; ++r) {
        int orow = orow0 + r;
        if (orow < n) {
            #pragma unroll
            for (int i = 0; i < 4; ++i)
                out[(size_t)orow * 128 + (ntBase + i) * 16 + col0] = f2bf(fmaxf(acc[i][r] + bb[i], 0.f));
        }
    }
}

// ---------------- MFMA GEMM (layers 2,3): hws = dis * (h_bf16 @ W) ----------------
// R19: 32 rows/wave (2 m-tiles share each weight-fragment load). bounds (256,4).
// Stores CACHED: A-writes warm L2 for the following k_agg gather.

__global__ __launch_bounds__(256, 4) void k_gemm_bf32(const ushort* __restrict__ in,
                                                      const ushort* __restrict__ Whi,
                                                      const ushort* __restrict__ Wlo,
                                                      const float* __restrict__ dis,
                                                      ushort* __restrict__ out, int n) {
    const int wave = threadIdx.x >> 6;
    const int lane = threadIdx.x & 63;
    const int m0 = (blockIdx.x * 4 + wave) * 32;
    if (m0 >= n) return;
    int row0 = m0 + (lane & 15);
    int row1 = row0 + 16;
    if (row0 >= n) row0 = n - 1;
    if (row1 >= n) row1 = n - 1;
    const int kh = (lane >> 4) * 8;
    const ushort* rp0 = in + (size_t)row0 * 128 + kh;
    const ushort* rp1 = in + (size_t)row1 * 128 + kh;

    v4f acc0[8], acc1[8];
    #pragma unroll
    for (int t = 0; t < 8; ++t) {
        acc0[t] = (v4f){0.f, 0.f, 0.f, 0.f};
        acc1[t] = (v4f){0.f, 0.f, 0.f, 0.f};
    }

    #pragma unroll
    for (int ks = 0; ks < 4; ++ks) {
        v8s a0 = *(const v8s*)(rp0 + ks * 32);
        v8s a1 = *(const v8s*)(rp1 + ks * 32);
        const ushort* bh = Whi + (size_t)(ks * 8) * 512 + (size_t)lane * 8;
        const ushort* bl = Wlo + (size_t)(ks * 8) * 512 + (size_t)lane * 8;
        #pragma unroll
        for (int nt = 0; nt < 8; ++nt) {
            v8s bhi = *(const v8s*)(bh + nt * 512);
            v8s blo = *(const v8s*)(bl + nt * 512);
            acc0[nt] = __builtin_amdgcn_mfma_f32_16x16x32_bf16(a0, bhi, acc0[nt], 0, 0, 0);
            acc0[nt] = __builtin_amdgcn_mfma_f32_16x16x32_bf16(a0, blo, acc0[nt], 0, 0, 0);
            acc1[nt] = __builtin_amdgcn_mfma_f32_16x16x32_bf16(a1, bhi, acc1[nt], 0, 0, 0);
            acc1[nt] = __builtin_amdgcn_mfma_f32_16x16x32_bf16(a1, blo, acc1[nt], 0, 0, 0);
        }
    }

    const int col0 = lane & 15;
    const int orow0 = m0 + (lane >> 4) * 4;
    #pragma unroll
    for (int r = 0; r < 4; ++r) {
        int orow = orow0 + r;
        if (orow < n) {
            float dv = dis[orow];
            #pragma unroll
            for (int nt = 0; nt < 8; ++nt)
                out[(size_t)orow * 128 + nt * 16 + col0] = f2bf(acc0[nt][r] * dv);
        }
        int orow2 = orow + 16;
        if (orow2 < n) {
            float dv = dis[orow2];
            #pragma unroll
            for (int nt = 0; nt < 8; ++nt)
                out[(size_t)orow2 * 128 + nt * 16 + col0] = f2bf(acc1[nt][r] * dv);
        }
    }
}

// ---------------- aggregation (layers 2,3): channel-split, merged halves ----------------
// out[i][:] = bf16( relu( dis[i]*( sum_j hws[col[j]] + hws[i] ) + b ) )
// R16/R20: one 128-B line per edge per half; both halves in ONE dispatch.
// 8-deep/(256,6) is the measured local optimum (94.2us / 297 MB / 3.45 TB/s);
// R12 showed occupancy and FETCH trade off against each other.

__global__ __launch_bounds__(256, 6) void k_agg(const ushort* __restrict__ hws, const int* __restrict__ rp,
                                                const int* __restrict__ col, const float* __restrict__ dis,
                                                const float* __restrict__ bias, ushort* __restrict__ out, int n) {
    int g = blockIdx.x * 32 + (threadIdx.x >> 3);   // group id in [0, 2n)
    int node = (g < n) ? g : g - n;                 // half0: ch 0-63, half1: ch 64-127
    if (g >= 2 * n) return;
    int c8 = ((g < n) ? 0 : 64) + ((threadIdx.x & 7) << 3);
    int s = rp[node], e = rp[node + 1];
    float A[8] = {0.f, 0.f, 0.f, 0.f, 0.f, 0.f, 0.f, 0.f};
    float B[8] = {0.f, 0.f, 0.f, 0.f, 0.f, 0.f, 0.f, 0.f};
    int j = s;
    for (; j + 7 < e; j += 8) {
        int c0 = col[j],     c1 = col[j + 1], c2 = col[j + 2], c3 = col[j + 3];
        int c4 = col[j + 4], c5 = col[j + 5], c6 = col[j + 6], c7 = col[j + 7];
        uint4 q0 = *(const uint4*)(hws + ((size_t)c0 << 7) + c8);
        uint4 q1 = *(const uint4*)(hws + ((size_t)c1 << 7) + c8);
        uint4 q2 = *(const uint4*)(hws + ((size_t)c2 << 7) + c8);
        uint4 q3 = *(const uint4*)(hws + ((size_t)c3 << 7) + c8);
        uint4 q4 = *(const uint4*)(hws + ((size_t)c4 << 7) + c8);
        uint4 q5 = *(const uint4*)(hws + ((size_t)c5 << 7) + c8);
        uint4 q6 = *(const uint4*)(hws + ((size_t)c6 << 7) + c8);
        uint4 q7 = *(const uint4*)(hws + ((size_t)c7 << 7) + c8);
        bfadd(A, q0); bfadd(B, q1); bfadd(A, q2); bfadd(B, q3);
        bfadd(A, q4); bfadd(B, q5); bfadd(A, q6); bfadd(B, q7);
    }
    if (j + 3 < e) {
        int c0 = col[j], c1 = col[j + 1], c2 = col[j + 2], c3 = col[j + 3];
        uint4 q0 = *(const uint4*)(hws + ((size_t)c0 << 7) + c8);
        uint4 q1 = *(const uint4*)(hws + ((size_t)c1 << 7) + c8);
        uint4 q2 = *(const uint4*)(hws + ((size_t)c2 << 7) + c8);
        uint4 q3 = *(const uint4*)(hws + ((size_t)c3 << 7) + c8);
        bfadd(A, q0); bfadd(B, q1); bfadd(A, q2); bfadd(B, q3);
        j += 4;
    }
    for (; j < e; ++j) {
        int c = col[j];
        uint4 q = *(const uint4*)(hws + ((size_t)c << 7) + c8);
        bfadd(A, q);
    }
    uint4 qs = *(const uint4*)(hws + ((size_t)node << 7) + c8);
    bfadd(A, qs);
    float dv = dis[node];
    float4 bv0 = *(const float4*)(bias + c8);
    float4 bv1 = *(const float4*)(bias + c8 + 4);
    float r0 = fmaxf(dv * (A[0] + B[0]) + bv0.x, 0.f);
    float r1 = fmaxf(dv * (A[1] + B[1]) + bv0.y, 0.f);
    float r2 = fmaxf(dv * (A[2] + B[2]) + bv0.z, 0.f);
    float r3 = fmaxf(dv * (A[3] + B[3]) + bv0.w, 0.f);
    float r4 = fmaxf(dv * (A[4] + B[4]) + bv1.x, 0.f);
    float r5 = fmaxf(dv * (A[5] + B[5]) + bv1.y, 0.f);
    float r6 = fmaxf(dv * (A[6] + B[6]) + bv1.z, 0.f);
    float r7 = fmaxf(dv * (A[7] + B[7]) + bv1.w, 0.f);
    uint4 o;
    o.x = pack2(r0, r1);
    o.y = pack2(r2, r3);
    o.z = pack2(r4, r5);
    o.w = pack2(r6, r7);
    *(uint4*)(out + (size_t)node * 128 + c8) = o;
}

// ---------------- fused mean-pool + heads (bf16 h input) ----------------

__global__ __launch_bounds__(256) void k_pool_head(const ushort* __restrict__ h, const int* __restrict__ batch,
                                                   const float* __restrict__ Wmu, const float* __restrict__ bmu,
                                                   const float* __restrict__ Wlv, const float* __restrict__ blv,
                                                   float* __restrict__ out, int n) {
    int g = blockIdx.x;
    int t = threadIdx.x;
    int lo = 0, hi = n;
    while (lo < hi) { int m = (lo + hi) >> 1; if (batch[m] < g) lo = m + 1; else hi = m; }
    int start = lo;
    hi = n;
    while (lo < hi) { int m = (lo + hi) >> 1; if (batch[m] < g + 1) lo = m + 1; else hi = m; }
    int end = lo;

    __shared__ float sh0[256];
    __shared__ float sh1[256];
    __shared__ float pooled[128];
    int lane = t & 63;
    int grp = t >> 6;
    float a0 = 0.f, a1 = 0.f;
    for (int i = start + grp; i < end; i += 4) {
        uint q = *(const uint*)(h + (size_t)i * 128 + lane * 2);
        a0 += bf_lo(q);
        a1 += bf_hi(q);
    }
    sh0[t] = a0;
    sh1[t] = a1;
    __syncthreads();
    if (t < 64) {
        float cnt = (float)(end - start);
        float inv = 1.0f / fmaxf(cnt, 1.0f);
        float s0 = sh0[t] + sh0[t + 64] + sh0[t + 128] + sh0[t + 192];
        float s1 = sh1[t] + sh1[t + 64] + sh1[t + 128] + sh1[t + 192];
        pooled[t * 2] = s0 * inv;
        pooled[t * 2 + 1] = s1 * inv;
    }
    __syncthreads();
    float amu = bmu[t], alv = blv[t];
    for (int k = 0; k < 128; k += 4) {
        float p0 = pooled[k], p1 = pooled[k + 1], p2 = pooled[k + 2], p3 = pooled[k + 3];
        amu += p0 * Wmu[(k + 0) * 256 + t] + p1 * Wmu[(k + 1) * 256 + t]
             + p2 * Wmu[(k + 2) * 256 + t] + p3 * Wmu[(k + 3) * 256 + t];
        alv += p0 * Wlv[(k + 0) * 256 + t] + p1 * Wlv[(k + 1) * 256 + t]
             + p2 * Wlv[(k + 2) * 256 + t] + p3 * Wlv[(k + 3) * 256 + t];
    }
    out[(size_t)g * 256 + t] = amu;
    out[(size_t)N_GRAPHS * 256 + (size_t)g * 256 + t] = alv;
}

// ---------------- launch ----------------

extern "C" void kernel_launch(void* const* d_in, const int* in_sizes, int n_in,
                              void* d_out, int out_size, void* d_ws, size_t ws_size,
                              hipStream_t stream) {
    const float* x    = (const float*)d_in[0];
    const int*   eidx = (const int*)d_in[1];
    const int*   batch= (const int*)d_in[2];
    const float* W1   = (const float*)d_in[3];
    const float* b1   = (const float*)d_in[4];
    const float* W2   = (const float*)d_in[5];
    const float* b2   = (const float*)d_in[6];
    const float* W3   = (const float*)d_in[7];
    const float* b3   = (const float*)d_in[8];
    const float* Wmu  = (const float*)d_in[9];
    const float* bmu  = (const float*)d_in[10];
    const float* Wlv  = (const float*)d_in[11];
    const float* blv  = (const float*)d_in[12];
    float* out = (float*)d_out;

    const int N = N_NODES, E = N_EDGES;
    const int* srcp = eidx;
    const int* dstp = eidx + E;

    // workspace layout
    ushort* w1h = (ushort*)d_ws;            // 4096
    ushort* w1l = w1h + 4096;               // 4096
    ushort* w2h = w1l + 4096;               // 16384
    ushort* w2l = w2h + 16384;              // 16384
    ushort* w3h = w2l + 16384;              // 16384
    ushort* w3l = w3h + 16384;              // 16384
    ushort* A   = w3l + 16384;              // N*128 bf16 (hws, gathered)
    ushort* B   = A + (size_t)N * 128;      // N*128 bf16 (h)
    float*  dis = (float*)(B + (size_t)N * 128);  // N
    int*   rp   = (int*)(dis + N);          // N+1 (pad 2)
    int*   bktCnt   = rp + (N + 2);         // NB (pad 512)
    int*   colStart = bktCnt + 512;         // NB+1 (pad 512) — unused since R22
    int*   packed = colStart + 512;         // NB*CAP
    int*   col    = packed + (size_t)NB * CAP;  // E

    // layer-1 fp32 table aliases A (dead until k_gemm_bf32 writes it):
    // xt = N*32 f32 (12.8 MB). y lives in LDS only (R22 fusion).
    float* xt = (float*)A;

    const int gE8192 = (E + 8191) / 8192;   // 391

    // W packs + bktCnt zeroing (one launch, runs before binA)
    k_pack_all<<<144, 256, 0, stream>>>(W1, W2, W3, w1h, w1l, w2h, w2l, w3h, w3l, bktCnt);

    // single-pass binned CSR build; binB folds bscan + emits xt
    k_binA<<<gE8192, 1024, 0, stream>>>(srcp, dstp, bktCnt, packed, E);
    k_binB<<<NB, 1024, 0, stream>>>(bktCnt, packed, col, rp, dis, x, xt, N);

    const int gGemm2 = (N + 127) / 128;     // 782  (32 rows/wave)
    const int gL1    = (N + 31) / 32;       // 3125 (32 nodes/block)
    const int gAgg   = (2 * N + 31) / 32;   // 6250: both halves, one dispatch

    // layer 1: fused 29-dim agg + GEMM(+bias+relu)
    k_l1<<<gL1, 256, 0, stream>>>(xt, rp, col, dis, w1h, w1l, b1, B, N);

    // layers 2,3: GEMM -> agg(+bias+relu), merged channel-halves
    k_gemm_bf32<<<gGemm2, 256, 0, stream>>>(B, w2h, w2l, dis, A, N);
    k_agg<<<gAgg, 256, 0, stream>>>(A, rp, col, dis, b2, B, N);
    k_gemm_bf32<<<gGemm2, 256, 0, stream>>>(B, w3h, w3l, dis, A, N);
    k_agg<<<gAgg, 256, 0, stream>>>(A, rp, col, dis, b3, B, N);
    k_pool_head<<<N_GRAPHS, 256, 0, stream>>>(B, batch, Wmu, bmu, Wlv, blv, out, N);
}

// Round 15
// 449.000 us; speedup vs baseline: 1.1616x; 1.0277x over previous
//
#include <hip/hip_runtime.h>
#include <hip/hip_bf16.h>

#define N_NODES 100000
#define N_EDGES 3200000
#define N_GRAPHS 512
#define IN_DIM 29
#define HID 128
#define LAT 256
#define NB 391     // ceil(N_NODES/256) dst-buckets
#define CAP 9216   // per-bucket packed capacity (mean 8184, sigma~90 -> +11 sigma)

typedef unsigned int uint;
typedef unsigned short ushort;
typedef float v4f __attribute__((ext_vector_type(4)));
typedef short v8s __attribute__((ext_vector_type(8)));

// round-to-nearest-even fp32 -> bf16 (finite inputs)
__device__ __forceinline__ ushort f2bf(float f) {
    uint u = __float_as_uint(f);
    return (ushort)((u + 0x7FFFu + ((u >> 16) & 1u)) >> 16);
}
__device__ __forceinline__ float bf2f(ushort h) { return __uint_as_float(((uint)h) << 16); }
__device__ __forceinline__ float bf_lo(uint p) { return __uint_as_float(p << 16); }
__device__ __forceinline__ float bf_hi(uint p) { return __uint_as_float(p & 0xFFFF0000u); }
__device__ __forceinline__ uint pack2(float a, float b) {
    return (uint)f2bf(a) | ((uint)f2bf(b) << 16);
}

__device__ __forceinline__ void bfadd(float* a, uint4 q) {
    a[0] += bf_lo(q.x); a[1] += bf_hi(q.x);
    a[2] += bf_lo(q.y); a[3] += bf_hi(q.y);
    a[4] += bf_lo(q.z); a[5] += bf_hi(q.z);
    a[6] += bf_lo(q.w); a[7] += bf_hi(q.w);
}

__device__ __forceinline__ v4f bf4(uint2 q) {
    return (v4f){bf_lo(q.x), bf_hi(q.x), bf_lo(q.y), bf_hi(q.y)};
}

// ---------------- preprocessing ----------------

// Single-pass binning: 1024 threads x 8 edges = 8192 edges/block (fat blocks
// win BECAUSE of store combining: R13's 256-thread variant caused 7x write
// amplification, 96us vs 32us). bin by dst>>8 into fixed-stride CAP regions.
// pack (dst&255)<<17 | src.
__global__ __launch_bounds__(1024, 2) void k_binA(const int* __restrict__ src, const int* __restrict__ dst,
                                                  int* __restrict__ bktCnt, int* __restrict__ packed, int e) {
    __shared__ int hist[NB];
    __shared__ int base[NB];
    int t = threadIdx.x;
    for (int i = t; i < NB; i += 1024) hist[i] = 0;
    __syncthreads();
    int d[8], s[8];
    const int blockStart = blockIdx.x * 8192;
    #pragma unroll
    for (int k = 0; k < 8; ++k) {
        int idx = blockStart + k * 1024 + t;
        if (idx < e) {
            d[k] = dst[idx];
            s[k] = src[idx];
            atomicAdd(&hist[d[k] >> 8], 1);
        } else d[k] = -1;
    }
    __syncthreads();
    for (int i = t; i < NB; i += 1024) {
        int c = hist[i];
        base[i] = c ? atomicAdd(&bktCnt[i], c) : 0;   // bucket-local offset
    }
    __syncthreads();
    #pragma unroll
    for (int k = 0; k < 8; ++k) {
        if (d[k] >= 0) {
            int b = d[k] >> 8;
            int pos = atomicAdd(&base[b], 1);
            if (pos < CAP) packed[b * CAP + pos] = ((d[k] & 255) << 17) | s[k];
        }
    }
}

// Phase B: per bucket, 1024 threads. R22: k_bscan folded in (per-block prefix
// over bktCnt). R26: pkb staging REVERTED (R14 measured null — binB is not
// global-latency-bound in the scatter pass); xt now written as BF16 (64-B
// rows) halving k_l1's gather table to 6.4 MB. Count per-(node, src-segment)
// keys (seg = src>>12), scan 8192 keys -> rp & dis + cursors, scatter col
// grouped by (node, seg) seg-ascending. R19: k_scale fused (bf16 now).
__global__ __launch_bounds__(1024, 2) void k_binB(const int* __restrict__ bktCnt,
                                                  const int* __restrict__ packed, int* __restrict__ col,
                                                  int* __restrict__ rp, float* __restrict__ dis,
                                                  const float* __restrict__ x, ushort* __restrict__ xt16, int n) {
    __shared__ int cnt[8192];     // 32 KB: per-(node,seg) counts -> cursors
    __shared__ int sh[1024];      // 4 KB: block scan / reduce buffer
    __shared__ float sdis[256];   // 1 KB: dis for this bucket's nodes
    const int b = blockIdx.x;
    int cntB = bktCnt[b];
    if (cntB > CAP) cntB = CAP;
    const int segS = b * CAP;
    int t = threadIdx.x;
    // folded bscan: prefix over buckets < b
    int part = 0;
    for (int i = t; i < b; i += 1024) {
        int c = bktCnt[i];
        part += (c > CAP) ? CAP : c;
    }
    #pragma unroll
    for (int k = 0; k < 8; ++k) cnt[t + k * 1024] = 0;
    sh[t] = part;
    __syncthreads();
    for (int off = 512; off > 0; off >>= 1) {
        if (t < off) sh[t] += sh[t + off];
        __syncthreads();
    }
    const int colBase = sh[0];
    // (sh reused below only after the counting barrier -> no extra sync needed)
    for (int j = t; j < cntB; j += 1024) {
        int pk = packed[segS + j];
        int key = ((pk >> 17) << 5) | ((pk & 0x1FFFF) >> 12);
        atomicAdd(&cnt[key], 1);
    }
    __syncthreads();
    // exclusive scan of cnt[8192]: thread t owns keys [8t, 8t+8)
    int base8 = t << 3;
    int v[8];
    int sum = 0;
    #pragma unroll
    for (int k = 0; k < 8; ++k) { v[k] = cnt[base8 + k]; sum += v[k]; }
    sh[t] = sum;
    __syncthreads();
    for (int off = 1; off < 1024; off <<= 1) {
        int x2 = (t >= off) ? sh[t - off] : 0;
        __syncthreads();
        sh[t] += x2;
        __syncthreads();
    }
    int run = colBase + sh[t] - sum;
    #pragma unroll
    for (int k = 0; k < 8; ++k) { cnt[base8 + k] = run; run += v[k]; }
    __syncthreads();
    if (t < 256) {
        int node = (b << 8) + t;
        int start = cnt[t << 5];
        int next = (t == 255) ? (colBase + cntB) : cnt[(t + 1) << 5];
        int deg = next - start;
        float dv = rsqrtf((float)deg + 1.0f);
        sdis[t] = dv;
        if (node <= n) rp[node] = start;      // node==n (last bucket) -> rp[n] = E
        if (node < n) dis[node] = dv;
    }
    __syncthreads();
    // fused x-tilde (bf16): xt16[node][k] = bf16(dis[node]*x[node][k]) (k<29), 0 pad
    for (int idx = t; idx < 256 * 32; idx += 1024) {
        int loc = idx >> 5;
        int node = (b << 8) + loc;
        if (node < n) {
            int k = idx & 31;
            float vv = (k < IN_DIM) ? x[(size_t)node * IN_DIM + k] * sdis[loc] : 0.f;
            xt16[((size_t)node << 5) + k] = f2bf(vv);
        }
    }
    for (int j = t; j < cntB; j += 1024) {
        int pk = packed[segS + j];
        int key = ((pk >> 17) << 5) | ((pk & 0x1FFFF) >> 12);
        int pos = atomicAdd(&cnt[key], 1);
        col[pos] = pk & 0x1FFFF;
    }
}

// ---------------- W pack (all 3 layers) + zero bktCnt (runs first) ----------------
// layout index = ((kstep*8 + ntile)*64 + lane)*8 + j
// element = W[kstep*32 + (lane>>4)*8 + j][ntile*16 + (lane&15)]

__device__ __forceinline__ void pack_one(const float* W, ushort* hi, ushort* lo, int Ksrc, int idx) {
    int j = idx & 7;
    int lane = (idx >> 3) & 63;
    int nt = (idx >> 9) & 7;
    int ks = idx >> 12;
    int k = ks * 32 + (lane >> 4) * 8 + j;
    int n = nt * 16 + (lane & 15);
    float v = (k < Ksrc) ? W[k * 128 + n] : 0.f;
    ushort h = f2bf(v);
    ushort l = f2bf(v - bf2f(h));
    hi[idx] = h;
    lo[idx] = l;
}

__global__ __launch_bounds__(256) void k_pack_all(const float* __restrict__ W1, const float* __restrict__ W2,
                                                  const float* __restrict__ W3,
                                                  ushort* w1h, ushort* w1l, ushort* w2h, ushort* w2l,
                                                  ushort* w3h, ushort* w3l, int* __restrict__ bktCnt) {
    int idx = blockIdx.x * 256 + threadIdx.x;
    if (idx < NB) bktCnt[idx] = 0;        // fold the zeroing launch in here
    if (idx < 4096) {
        pack_one(W1, w1h, w1l, IN_DIM, idx);
    } else if (idx < 4096 + 16384) {
        pack_one(W2, w2h, w2l, HID, idx - 4096);
    } else if (idx < 4096 + 32768) {
        pack_one(W3, w3h, w3l, HID, idx - 4096 - 16384);
    }
}

// ---------------- layer 1 fused: 29-dim agg + GEMM + bias + relu (R22/R26) ----------------
// Block = 256 threads = 32 consecutive nodes (N = 3125*32 exactly).
// Phase 1 (agg): 8 lanes/node, 4 bf16 channels/lane (uint2 = 8 B half-line
// gather from the 6.4 MB bf16 x-tilde table — R26: bytes halved vs fp32,
// 2 nodes/128B-line -> much better L2 residency); fp32 accumulate; y-row ->
// LDS [32][36] fp32. Phase 2 (gemm): 4 waves, wave w: m-tile (w>>1), nt
// range (w&1)*4..+4; split-precision Yhi@Whi + Yhi@Wlo + Ylo@Whi; bias+relu
// epilogue. y never touches HBM.

__global__ __launch_bounds__(256, 6) void k_l1(const ushort* __restrict__ xt16, const int* __restrict__ rp,
                                               const int* __restrict__ col, const float* __restrict__ dis,
                                               const ushort* __restrict__ Whi, const ushort* __restrict__ Wlo,
                                               const float* __restrict__ bias, ushort* __restrict__ out, int n) {
    __shared__ float yl[32][36];
    int t = threadIdx.x;
    int loc = t >> 3;
    int node = blockIdx.x * 32 + loc;
    int c4 = (t & 7) << 2;
    if (node < n) {
        int s = rp[node], e = rp[node + 1];
        v4f A = (v4f){0.f, 0.f, 0.f, 0.f};
        v4f B = (v4f){0.f, 0.f, 0.f, 0.f};
        int j = s;
        for (; j + 7 < e; j += 8) {
            int c0 = col[j],     c1 = col[j + 1], c2 = col[j + 2], c3 = col[j + 3];
            int c4i = col[j + 4], c5 = col[j + 5], c6 = col[j + 6], c7 = col[j + 7];
            uint2 q0 = *(const uint2*)(xt16 + ((size_t)c0 << 5) + c4);
            uint2 q1 = *(const uint2*)(xt16 + ((size_t)c1 << 5) + c4);
            uint2 q2 = *(const uint2*)(xt16 + ((size_t)c2 << 5) + c4);
            uint2 q3 = *(const uint2*)(xt16 + ((size_t)c3 << 5) + c4);
            uint2 q4 = *(const uint2*)(xt16 + ((size_t)c4i << 5) + c4);
            uint2 q5 = *(const uint2*)(xt16 + ((size_t)c5 << 5) + c4);
            uint2 q6 = *(const uint2*)(xt16 + ((size_t)c6 << 5) + c4);
            uint2 q7 = *(const uint2*)(xt16 + ((size_t)c7 << 5) + c4);
            A += bf4(q0); B += bf4(q1); A += bf4(q2); B += bf4(q3);
            A += bf4(q4); B += bf4(q5); A += bf4(q6); B += bf4(q7);
        }
        if (j + 3 < e) {
            int c0 = col[j], c1 = col[j + 1], c2 = col[j + 2], c3 = col[j + 3];
            uint2 q0 = *(const uint2*)(xt16 + ((size_t)c0 << 5) + c4);
            uint2 q1 = *(const uint2*)(xt16 + ((size_t)c1 << 5) + c4);
            uint2 q2 = *(const uint2*)(xt16 + ((size_t)c2 << 5) + c4);
            uint2 q3 = *(const uint2*)(xt16 + ((size_t)c3 << 5) + c4);
            A += bf4(q0); B += bf4(q1); A += bf4(q2); B += bf4(q3);
            j += 4;
        }
        for (; j < e; ++j) {
            int c = col[j];
            A += bf4(*(const uint2*)(xt16 + ((size_t)c << 5) + c4));
        }
        A += bf4(*(const uint2*)(xt16 + ((size_t)node << 5) + c4));
        float dv = dis[node];
        v4f o = (A + B) * dv;
        yl[loc][c4 + 0] = o.x;
        yl[loc][c4 + 1] = o.y;
        yl[loc][c4 + 2] = o.z;
        yl[loc][c4 + 3] = o.w;
    }
    __syncthreads();
    // gemm phase
    const int wave = t >> 6;
    const int lane = t & 63;
    const int mrow = ((wave >> 1) << 4) + (lane & 15);   // local row 0..31
    const int ntBase = (wave & 1) * 4;
    const int kh = (lane >> 4) * 8;
    float a[8];
    #pragma unroll
    for (int j = 0; j < 8; ++j) a[j] = yl[mrow][kh + j];
    v8s ahi, alo;
    #pragma unroll
    for (int j = 0; j < 8; ++j) {
        ushort h = f2bf(a[j]);
        ushort l = f2bf(a[j] - bf2f(h));
        ahi[j] = (short)h;
        alo[j] = (short)l;
    }
    const ushort* bh = Whi + (size_t)lane * 8;
    const ushort* bl = Wlo + (size_t)lane * 8;
    v4f acc[4];
    #pragma unroll
    for (int i = 0; i < 4; ++i) acc[i] = (v4f){0.f, 0.f, 0.f, 0.f};
    #pragma unroll
    for (int i = 0; i < 4; ++i) {
        int nt = ntBase + i;
        v8s bhi = *(const v8s*)(bh + nt * 512);
        v8s blo = *(const v8s*)(bl + nt * 512);
        acc[i] = __builtin_amdgcn_mfma_f32_16x16x32_bf16(ahi, bhi, acc[i], 0, 0, 0);
        acc[i] = __builtin_amdgcn_mfma_f32_16x16x32_bf16(ahi, blo, acc[i], 0, 0, 0);
        acc[i] = __builtin_amdgcn_mfma_f32_16x16x32_bf16(alo, bhi, acc[i], 0, 0, 0);
    }
    const int col0 = lane & 15;
    const int orow0 = blockIdx.x * 32 + ((wave >> 1) << 4) + ((lane >> 4) << 2);
    float bb[4];
    #pragma unroll
    for (int i = 0; i < 4; ++i) bb[i] = bias[(ntBase + i) * 16 + col0];
    #pragma unroll
    for (int r = 0; r < 4; ++r) {
        int orow = orow0 + r;
        if (orow < n) {
            #pragma unroll
            for (int i = 0; i < 4; ++i)
                out[(size_t)orow * 128 + (ntBase + i) * 16 + col0] = f2bf(fmaxf(acc[i][r] + bb[i], 0.f));
        }
    }
}

// ---------------- MFMA GEMM (layers 2,3): hws = dis * (h_bf16 @ W) ----------------
// R19: 32 rows/wave (2 m-tiles share each weight-fragment load). bounds (256,4).
// Stores CACHED: A-writes warm L2 for the following k_agg gather.

__global__ __launch_bounds__(256, 4) void k_gemm_bf32(const ushort* __restrict__ in,
                                                      const ushort* __restrict__ Whi,
                                                      const ushort* __restrict__ Wlo,
                                                      const float* __restrict__ dis,
                                                      ushort* __restrict__ out, int n) {
    const int wave = threadIdx.x >> 6;
    const int lane = threadIdx.x & 63;
    const int m0 = (blockIdx.x * 4 + wave) * 32;
    if (m0 >= n) return;
    int row0 = m0 + (lane & 15);
    int row1 = row0 + 16;
    if (row0 >= n) row0 = n - 1;
    if (row1 >= n) row1 = n - 1;
    const int kh = (lane >> 4) * 8;
    const ushort* rp0 = in + (size_t)row0 * 128 + kh;
    const ushort* rp1 = in + (size_t)row1 * 128 + kh;

    v4f acc0[8], acc1[8];
    #pragma unroll
    for (int t = 0; t < 8; ++t) {
        acc0[t] = (v4f){0.f, 0.f, 0.f, 0.f};
        acc1[t] = (v4f){0.f, 0.f, 0.f, 0.f};
    }

    #pragma unroll
    for (int ks = 0; ks < 4; ++ks) {
        v8s a0 = *(const v8s*)(rp0 + ks * 32);
        v8s a1 = *(const v8s*)(rp1 + ks * 32);
        const ushort* bh = Whi + (size_t)(ks * 8) * 512 + (size_t)lane * 8;
        const ushort* bl = Wlo + (size_t)(ks * 8) * 512 + (size_t)lane * 8;
        #pragma unroll
        for (int nt = 0; nt < 8; ++nt) {
            v8s bhi = *(const v8s*)(bh + nt * 512);
            v8s blo = *(const v8s*)(bl + nt * 512);
            acc0[nt] = __builtin_amdgcn_mfma_f32_16x16x32_bf16(a0, bhi, acc0[nt], 0, 0, 0);
            acc0[nt] = __builtin_amdgcn_mfma_f32_16x16x32_bf16(a0, blo, acc0[nt], 0, 0, 0);
            acc1[nt] = __builtin_amdgcn_mfma_f32_16x16x32_bf16(a1, bhi, acc1[nt], 0, 0, 0);
            acc1[nt] = __builtin_amdgcn_mfma_f32_16x16x32_bf16(a1, blo, acc1[nt], 0, 0, 0);
        }
    }

    const int col0 = lane & 15;
    const int orow0 = m0 + (lane >> 4) * 4;
    #pragma unroll
    for (int r = 0; r < 4; ++r) {
        int orow = orow0 + r;
        if (orow < n) {
            float dv = dis[orow];
            #pragma unroll
            for (int nt = 0; nt < 8; ++nt)
                out[(size_t)orow * 128 + nt * 16 + col0] = f2bf(acc0[nt][r] * dv);
        }
        int orow2 = orow + 16;
        if (orow2 < n) {
            float dv = dis[orow2];
            #pragma unroll
            for (int nt = 0; nt < 8; ++nt)
                out[(size_t)orow2 * 128 + nt * 16 + col0] = f2bf(acc1[nt][r] * dv);
        }
    }
}

// ---------------- aggregation (layers 2,3): channel-split, merged halves ----------------
// out[i][:] = bf16( relu( dis[i]*( sum_j hws[col[j]] + hws[i] ) + b ) )
// R16/R20: one 128-B line per edge per half; both halves in ONE dispatch.
// 8-deep/(256,6) is the measured local optimum (94.2us / 297 MB / 3.45 TB/s);
// R12 showed occupancy and FETCH trade off against each other.

__global__ __launch_bounds__(256, 6) void k_agg(const ushort* __restrict__ hws, const int* __restrict__ rp,
                                                const int* __restrict__ col, const float* __restrict__ dis,
                                                const float* __restrict__ bias, ushort* __restrict__ out, int n) {
    int g = blockIdx.x * 32 + (threadIdx.x >> 3);   // group id in [0, 2n)
    int node = (g < n) ? g : g - n;                 // half0: ch 0-63, half1: ch 64-127
    if (g >= 2 * n) return;
    int c8 = ((g < n) ? 0 : 64) + ((threadIdx.x & 7) << 3);
    int s = rp[node], e = rp[node + 1];
    float A[8] = {0.f, 0.f, 0.f, 0.f, 0.f, 0.f, 0.f, 0.f};
    float B[8] = {0.f, 0.f, 0.f, 0.f, 0.f, 0.f, 0.f, 0.f};
    int j = s;
    for (; j + 7 < e; j += 8) {
        int c0 = col[j],     c1 = col[j + 1], c2 = col[j + 2], c3 = col[j + 3];
        int c4 = col[j + 4], c5 = col[j + 5], c6 = col[j + 6], c7 = col[j + 7];
        uint4 q0 = *(const uint4*)(hws + ((size_t)c0 << 7) + c8);
        uint4 q1 = *(const uint4*)(hws + ((size_t)c1 << 7) + c8);
        uint4 q2 = *(const uint4*)(hws + ((size_t)c2 << 7) + c8);
        uint4 q3 = *(const uint4*)(hws + ((size_t)c3 << 7) + c8);
        uint4 q4 = *(const uint4*)(hws + ((size_t)c4 << 7) + c8);
        uint4 q5 = *(const uint4*)(hws + ((size_t)c5 << 7) + c8);
        uint4 q6 = *(const uint4*)(hws + ((size_t)c6 << 7) + c8);
        uint4 q7 = *(const uint4*)(hws + ((size_t)c7 << 7) + c8);
        bfadd(A, q0); bfadd(B, q1); bfadd(A, q2); bfadd(B, q3);
        bfadd(A, q4); bfadd(B, q5); bfadd(A, q6); bfadd(B, q7);
    }
    if (j + 3 < e) {
        int c0 = col[j], c1 = col[j + 1], c2 = col[j + 2], c3 = col[j + 3];
        uint4 q0 = *(const uint4*)(hws + ((size_t)c0 << 7) + c8);
        uint4 q1 = *(const uint4*)(hws + ((size_t)c1 << 7) + c8);
        uint4 q2 = *(const uint4*)(hws + ((size_t)c2 << 7) + c8);
        uint4 q3 = *(const uint4*)(hws + ((size_t)c3 << 7) + c8);
        bfadd(A, q0); bfadd(B, q1); bfadd(A, q2); bfadd(B, q3);
        j += 4;
    }
    for (; j < e; ++j) {
        int c = col[j];
        uint4 q = *(const uint4*)(hws + ((size_t)c << 7) + c8);
        bfadd(A, q);
    }
    uint4 qs = *(const uint4*)(hws + ((size_t)node << 7) + c8);
    bfadd(A, qs);
    float dv = dis[node];
    float4 bv0 = *(const float4*)(bias + c8);
    float4 bv1 = *(const float4*)(bias + c8 + 4);
    float r0 = fmaxf(dv * (A[0] + B[0]) + bv0.x, 0.f);
    float r1 = fmaxf(dv * (A[1] + B[1]) + bv0.y, 0.f);
    float r2 = fmaxf(dv * (A[2] + B[2]) + bv0.z, 0.f);
    float r3 = fmaxf(dv * (A[3] + B[3]) + bv0.w, 0.f);
    float r4 = fmaxf(dv * (A[4] + B[4]) + bv1.x, 0.f);
    float r5 = fmaxf(dv * (A[5] + B[5]) + bv1.y, 0.f);
    float r6 = fmaxf(dv * (A[6] + B[6]) + bv1.z, 0.f);
    float r7 = fmaxf(dv * (A[7] + B[7]) + bv1.w, 0.f);
    uint4 o;
    o.x = pack2(r0, r1);
    o.y = pack2(r2, r3);
    o.z = pack2(r4, r5);
    o.w = pack2(r6, r7);
    *(uint4*)(out + (size_t)node * 128 + c8) = o;
}

// ---------------- fused mean-pool + heads (bf16 h input) ----------------

__global__ __launch_bounds__(256) void k_pool_head(const ushort* __restrict__ h, const int* __restrict__ batch,
                                                   const float* __restrict__ Wmu, const float* __restrict__ bmu,
                                                   const float* __restrict__ Wlv, const float* __restrict__ blv,
                                                   float* __restrict__ out, int n) {
    int g = blockIdx.x;
    int t = threadIdx.x;
    int lo = 0, hi = n;
    while (lo < hi) { int m = (lo + hi) >> 1; if (batch[m] < g) lo = m + 1; else hi = m; }
    int start = lo;
    hi = n;
    while (lo < hi) { int m = (lo + hi) >> 1; if (batch[m] < g + 1) lo = m + 1; else hi = m; }
    int end = lo;

    __shared__ float sh0[256];
    __shared__ float sh1[256];
    __shared__ float pooled[128];
    int lane = t & 63;
    int grp = t >> 6;
    float a0 = 0.f, a1 = 0.f;
    for (int i = start + grp; i < end; i += 4) {
        uint q = *(const uint*)(h + (size_t)i * 128 + lane * 2);
        a0 += bf_lo(q);
        a1 += bf_hi(q);
    }
    sh0[t] = a0;
    sh1[t] = a1;
    __syncthreads();
    if (t < 64) {
        float cnt = (float)(end - start);
        float inv = 1.0f / fmaxf(cnt, 1.0f);
        float s0 = sh0[t] + sh0[t + 64] + sh0[t + 128] + sh0[t + 192];
        float s1 = sh1[t] + sh1[t + 64] + sh1[t + 128] + sh1[t + 192];
        pooled[t * 2] = s0 * inv;
        pooled[t * 2 + 1] = s1 * inv;
    }
    __syncthreads();
    float amu = bmu[t], alv = blv[t];
    for (int k = 0; k < 128; k += 4) {
        float p0 = pooled[k], p1 = pooled[k + 1], p2 = pooled[k + 2], p3 = pooled[k + 3];
        amu += p0 * Wmu[(k + 0) * 256 + t] + p1 * Wmu[(k + 1) * 256 + t]
             + p2 * Wmu[(k + 2) * 256 + t] + p3 * Wmu[(k + 3) * 256 + t];
        alv += p0 * Wlv[(k + 0) * 256 + t] + p1 * Wlv[(k + 1) * 256 + t]
             + p2 * Wlv[(k + 2) * 256 + t] + p3 * Wlv[(k + 3) * 256 + t];
    }
    out[(size_t)g * 256 + t] = amu;
    out[(size_t)N_GRAPHS * 256 + (size_t)g * 256 + t] = alv;
}

// ---------------- launch ----------------

extern "C" void kernel_launch(void* const* d_in, const int* in_sizes, int n_in,
                              void* d_out, int out_size, void* d_ws, size_t ws_size,
                              hipStream_t stream) {
    const float* x    = (const float*)d_in[0];
    const int*   eidx = (const int*)d_in[1];
    const int*   batch= (const int*)d_in[2];
    const float* W1   = (const float*)d_in[3];
    const float* b1   = (const float*)d_in[4];
    const float* W2   = (const float*)d_in[5];
    const float* b2   = (const float*)d_in[6];
    const float* W3   = (const float*)d_in[7];
    const float* b3   = (const float*)d_in[8];
    const float* Wmu  = (const float*)d_in[9];
    const float* bmu  = (const float*)d_in[10];
    const float* Wlv  = (const float*)d_in[11];
    const float* blv  = (const float*)d_in[12];
    float* out = (float*)d_out;

    const int N = N_NODES, E = N_EDGES;
    const int* srcp = eidx;
    const int* dstp = eidx + E;

    // workspace layout
    ushort* w1h = (ushort*)d_ws;            // 4096
    ushort* w1l = w1h + 4096;               // 4096
    ushort* w2h = w1l + 4096;               // 16384
    ushort* w2l = w2h + 16384;              // 16384
    ushort* w3h = w2l + 16384;              // 16384
    ushort* w3l = w3h + 16384;              // 16384
    ushort* A   = w3l + 16384;              // N*128 bf16 (hws, gathered)
    ushort* B   = A + (size_t)N * 128;      // N*128 bf16 (h)
    float*  dis = (float*)(B + (size_t)N * 128);  // N
    int*   rp   = (int*)(dis + N);          // N+1 (pad 2)
    int*   bktCnt   = rp + (N + 2);         // NB (pad 512)
    int*   colStart = bktCnt + 512;         // NB+1 (pad 512) — unused since R22
    int*   packed = colStart + 512;         // NB*CAP
    int*   col    = packed + (size_t)NB * CAP;  // E

    // layer-1 bf16 x-tilde table aliases A (dead until k_gemm_bf32 writes it):
    // xt16 = N*32 bf16 (6.4 MB). y lives in LDS only (R22 fusion).
    ushort* xt16 = A;

    const int gE8192 = (E + 8191) / 8192;   // 391

    // W packs + bktCnt zeroing (one launch, runs before binA)
    k_pack_all<<<144, 256, 0, stream>>>(W1, W2, W3, w1h, w1l, w2h, w2l, w3h, w3l, bktCnt);

    // single-pass binned CSR build; binB folds bscan + emits bf16 xt
    k_binA<<<gE8192, 1024, 0, stream>>>(srcp, dstp, bktCnt, packed, E);
    k_binB<<<NB, 1024, 0, stream>>>(bktCnt, packed, col, rp, dis, x, xt16, N);

    const int gGemm2 = (N + 127) / 128;     // 782  (32 rows/wave)
    const int gL1    = (N + 31) / 32;       // 3125 (32 nodes/block)
    const int gAgg   = (2 * N + 31) / 32;   // 6250: both halves, one dispatch

    // layer 1: fused 29-dim agg (bf16 table) + GEMM(+bias+relu)
    k_l1<<<gL1, 256, 0, stream>>>(xt16, rp, col, dis, w1h, w1l, b1, B, N);

    // layers 2,3: GEMM -> agg(+bias+relu), merged channel-halves
    k_gemm_bf32<<<gGemm2, 256, 0, stream>>>(B, w2h, w2l, dis, A, N);
    k_agg<<<gAgg, 256, 0, stream>>>(A, rp, col, dis, b2, B, N);
    k_gemm_bf32<<<gGemm2, 256, 0, stream>>>(B, w3h, w3l, dis, A, N);
    k_agg<<<gAgg, 256, 0, stream>>>(A, rp, col, dis, b3, B, N);
    k_pool_head<<<N_GRAPHS, 256, 0, stream>>>(B, batch, Wmu, bmu, Wlv, blv, out, N);
}

// Round 16
// 429.975 us; speedup vs baseline: 1.2130x; 1.0442x over previous
//
#include <hip/hip_runtime.h>
#include <hip/hip_bf16.h>

#define N_NODES 100000
#define N_EDGES 3200000
#define N_GRAPHS 512
#define IN_DIM 29
#define HID 128
#define LAT 256
#define NB 391     // ceil(N_NODES/256) dst-buckets
#define CAP 9216   // per-bucket packed capacity (mean 8184, sigma~90 -> +11 sigma)

typedef unsigned int uint;
typedef unsigned short ushort;
typedef float v4f __attribute__((ext_vector_type(4)));
typedef short v8s __attribute__((ext_vector_type(8)));

// round-to-nearest-even fp32 -> bf16 (finite inputs)
__device__ __forceinline__ ushort f2bf(float f) {
    uint u = __float_as_uint(f);
    return (ushort)((u + 0x7FFFu + ((u >> 16) & 1u)) >> 16);
}
__device__ __forceinline__ float bf2f(ushort h) { return __uint_as_float(((uint)h) << 16); }
__device__ __forceinline__ float bf_lo(uint p) { return __uint_as_float(p << 16); }
__device__ __forceinline__ float bf_hi(uint p) { return __uint_as_float(p & 0xFFFF0000u); }
__device__ __forceinline__ uint pack2(float a, float b) {
    return (uint)f2bf(a) | ((uint)f2bf(b) << 16);
}

__device__ __forceinline__ void bfadd(float* a, uint4 q) {
    a[0] += bf_lo(q.x); a[1] += bf_hi(q.x);
    a[2] += bf_lo(q.y); a[3] += bf_hi(q.y);
    a[4] += bf_lo(q.z); a[5] += bf_hi(q.z);
    a[6] += bf_lo(q.w); a[7] += bf_hi(q.w);
}

__device__ __forceinline__ v4f bf4(uint2 q) {
    return (v4f){bf_lo(q.x), bf_hi(q.x), bf_lo(q.y), bf_hi(q.y)};
}

// ---------------- preprocessing ----------------

// Single-pass binning: 1024 threads x 8 edges = 8192 edges/block (fat blocks
// win BECAUSE of store combining: R13's 256-thread variant caused 7x write
// amplification, 96us vs 32us). bin by dst>>8 into fixed-stride CAP regions.
// pack (dst&255)<<17 | src.
__global__ __launch_bounds__(1024, 2) void k_binA(const int* __restrict__ src, const int* __restrict__ dst,
                                                  int* __restrict__ bktCnt, int* __restrict__ packed, int e) {
    __shared__ int hist[NB];
    __shared__ int base[NB];
    int t = threadIdx.x;
    for (int i = t; i < NB; i += 1024) hist[i] = 0;
    __syncthreads();
    int d[8], s[8];
    const int blockStart = blockIdx.x * 8192;
    #pragma unroll
    for (int k = 0; k < 8; ++k) {
        int idx = blockStart + k * 1024 + t;
        if (idx < e) {
            d[k] = dst[idx];
            s[k] = src[idx];
            atomicAdd(&hist[d[k] >> 8], 1);
        } else d[k] = -1;
    }
    __syncthreads();
    for (int i = t; i < NB; i += 1024) {
        int c = hist[i];
        base[i] = c ? atomicAdd(&bktCnt[i], c) : 0;   // bucket-local offset
    }
    __syncthreads();
    #pragma unroll
    for (int k = 0; k < 8; ++k) {
        if (d[k] >= 0) {
            int b = d[k] >> 8;
            int pos = atomicAdd(&base[b], 1);
            if (pos < CAP) packed[b * CAP + pos] = ((d[k] & 255) << 17) | s[k];
        }
    }
}

// Phase B: per bucket, 1024 threads. R22: k_bscan folded in (per-block prefix
// over bktCnt). Count per-(node, src-segment) keys (seg = src>>12), scan 8192
// keys -> rp & dis + cursors, scatter col grouped by (node, seg) seg-ascending.
// R19/R26: k_scale fused — writes bf16 xt (64-B rows, 6.4 MB table).
__global__ __launch_bounds__(1024, 2) void k_binB(const int* __restrict__ bktCnt,
                                                  const int* __restrict__ packed, int* __restrict__ col,
                                                  int* __restrict__ rp, float* __restrict__ dis,
                                                  const float* __restrict__ x, ushort* __restrict__ xt16, int n) {
    __shared__ int cnt[8192];     // 32 KB: per-(node,seg) counts -> cursors
    __shared__ int sh[1024];      // 4 KB: block scan / reduce buffer
    __shared__ float sdis[256];   // 1 KB: dis for this bucket's nodes
    const int b = blockIdx.x;
    int cntB = bktCnt[b];
    if (cntB > CAP) cntB = CAP;
    const int segS = b * CAP;
    int t = threadIdx.x;
    // folded bscan: prefix over buckets < b
    int part = 0;
    for (int i = t; i < b; i += 1024) {
        int c = bktCnt[i];
        part += (c > CAP) ? CAP : c;
    }
    #pragma unroll
    for (int k = 0; k < 8; ++k) cnt[t + k * 1024] = 0;
    sh[t] = part;
    __syncthreads();
    for (int off = 512; off > 0; off >>= 1) {
        if (t < off) sh[t] += sh[t + off];
        __syncthreads();
    }
    const int colBase = sh[0];
    // (sh reused below only after the counting barrier -> no extra sync needed)
    for (int j = t; j < cntB; j += 1024) {
        int pk = packed[segS + j];
        int key = ((pk >> 17) << 5) | ((pk & 0x1FFFF) >> 12);
        atomicAdd(&cnt[key], 1);
    }
    __syncthreads();
    // exclusive scan of cnt[8192]: thread t owns keys [8t, 8t+8)
    int base8 = t << 3;
    int v[8];
    int sum = 0;
    #pragma unroll
    for (int k = 0; k < 8; ++k) { v[k] = cnt[base8 + k]; sum += v[k]; }
    sh[t] = sum;
    __syncthreads();
    for (int off = 1; off < 1024; off <<= 1) {
        int x2 = (t >= off) ? sh[t - off] : 0;
        __syncthreads();
        sh[t] += x2;
        __syncthreads();
    }
    int run = colBase + sh[t] - sum;
    #pragma unroll
    for (int k = 0; k < 8; ++k) { cnt[base8 + k] = run; run += v[k]; }
    __syncthreads();
    if (t < 256) {
        int node = (b << 8) + t;
        int start = cnt[t << 5];
        int next = (t == 255) ? (colBase + cntB) : cnt[(t + 1) << 5];
        int deg = next - start;
        float dv = rsqrtf((float)deg + 1.0f);
        sdis[t] = dv;
        if (node <= n) rp[node] = start;      // node==n (last bucket) -> rp[n] = E
        if (node < n) dis[node] = dv;
    }
    __syncthreads();
    // fused x-tilde (bf16): xt16[node][k] = bf16(dis[node]*x[node][k]) (k<29), 0 pad
    for (int idx = t; idx < 256 * 32; idx += 1024) {
        int loc = idx >> 5;
        int node = (b << 8) + loc;
        if (node < n) {
            int k = idx & 31;
            float vv = (k < IN_DIM) ? x[(size_t)node * IN_DIM + k] * sdis[loc] : 0.f;
            xt16[((size_t)node << 5) + k] = f2bf(vv);
        }
    }
    for (int j = t; j < cntB; j += 1024) {
        int pk = packed[segS + j];
        int key = ((pk >> 17) << 5) | ((pk & 0x1FFFF) >> 12);
        int pos = atomicAdd(&cnt[key], 1);
        col[pos] = pk & 0x1FFFF;
    }
}

// ---------------- W pack (all 3 layers) + zero bktCnt + zero pooled ----------------
// layout index = ((kstep*8 + ntile)*64 + lane)*8 + j
// element = W[kstep*32 + (lane>>4)*8 + j][ntile*16 + (lane&15)]

__device__ __forceinline__ void pack_one(const float* W, ushort* hi, ushort* lo, int Ksrc, int idx) {
    int j = idx & 7;
    int lane = (idx >> 3) & 63;
    int nt = (idx >> 9) & 7;
    int ks = idx >> 12;
    int k = ks * 32 + (lane >> 4) * 8 + j;
    int n = nt * 16 + (lane & 15);
    float v = (k < Ksrc) ? W[k * 128 + n] : 0.f;
    ushort h = f2bf(v);
    ushort l = f2bf(v - bf2f(h));
    hi[idx] = h;
    lo[idx] = l;
}

__global__ __launch_bounds__(256) void k_pack_all(const float* __restrict__ W1, const float* __restrict__ W2,
                                                  const float* __restrict__ W3,
                                                  ushort* w1h, ushort* w1l, ushort* w2h, ushort* w2l,
                                                  ushort* w3h, ushort* w3l, int* __restrict__ bktCnt,
                                                  float* __restrict__ pooled) {
    int idx = blockIdx.x * 256 + threadIdx.x;
    if (idx < NB) bktCnt[idx] = 0;        // fold the zeroing launch in here
    if (idx < N_GRAPHS * HID) pooled[idx] = 0.f;   // R27: zero pooled accumulator
    if (idx < 4096) {
        pack_one(W1, w1h, w1l, IN_DIM, idx);
    } else if (idx < 4096 + 16384) {
        pack_one(W2, w2h, w2l, HID, idx - 4096);
    } else if (idx < 4096 + 32768) {
        pack_one(W3, w3h, w3l, HID, idx - 4096 - 16384);
    }
}

// ---------------- layer 1 fused: 29-dim agg + GEMM + bias + relu (R22/R26) ----------------
// Block = 256 threads = 32 consecutive nodes (N = 3125*32 exactly).
// Phase 1 (agg): 8 lanes/node, 4 bf16 channels/lane (8-B half-line gather
// from the 6.4 MB bf16 x-tilde table); fp32 accumulate; y-row -> LDS [32][36].
// Phase 2 (gemm): 4 waves; split-precision Yhi@Whi + Yhi@Wlo + Ylo@Whi;
// bias+relu epilogue. y never touches HBM.

__global__ __launch_bounds__(256, 6) void k_l1(const ushort* __restrict__ xt16, const int* __restrict__ rp,
                                               const int* __restrict__ col, const float* __restrict__ dis,
                                               const ushort* __restrict__ Whi, const ushort* __restrict__ Wlo,
                                               const float* __restrict__ bias, ushort* __restrict__ out, int n) {
    __shared__ float yl[32][36];
    int t = threadIdx.x;
    int loc = t >> 3;
    int node = blockIdx.x * 32 + loc;
    int c4 = (t & 7) << 2;
    if (node < n) {
        int s = rp[node], e = rp[node + 1];
        v4f A = (v4f){0.f, 0.f, 0.f, 0.f};
        v4f B = (v4f){0.f, 0.f, 0.f, 0.f};
        int j = s;
        for (; j + 7 < e; j += 8) {
            int c0 = col[j],     c1 = col[j + 1], c2 = col[j + 2], c3 = col[j + 3];
            int c4i = col[j + 4], c5 = col[j + 5], c6 = col[j + 6], c7 = col[j + 7];
            uint2 q0 = *(const uint2*)(xt16 + ((size_t)c0 << 5) + c4);
            uint2 q1 = *(const uint2*)(xt16 + ((size_t)c1 << 5) + c4);
            uint2 q2 = *(const uint2*)(xt16 + ((size_t)c2 << 5) + c4);
            uint2 q3 = *(const uint2*)(xt16 + ((size_t)c3 << 5) + c4);
            uint2 q4 = *(const uint2*)(xt16 + ((size_t)c4i << 5) + c4);
            uint2 q5 = *(const uint2*)(xt16 + ((size_t)c5 << 5) + c4);
            uint2 q6 = *(const uint2*)(xt16 + ((size_t)c6 << 5) + c4);
            uint2 q7 = *(const uint2*)(xt16 + ((size_t)c7 << 5) + c4);
            A += bf4(q0); B += bf4(q1); A += bf4(q2); B += bf4(q3);
            A += bf4(q4); B += bf4(q5); A += bf4(q6); B += bf4(q7);
        }
        if (j + 3 < e) {
            int c0 = col[j], c1 = col[j + 1], c2 = col[j + 2], c3 = col[j + 3];
            uint2 q0 = *(const uint2*)(xt16 + ((size_t)c0 << 5) + c4);
            uint2 q1 = *(const uint2*)(xt16 + ((size_t)c1 << 5) + c4);
            uint2 q2 = *(const uint2*)(xt16 + ((size_t)c2 << 5) + c4);
            uint2 q3 = *(const uint2*)(xt16 + ((size_t)c3 << 5) + c4);
            A += bf4(q0); B += bf4(q1); A += bf4(q2); B += bf4(q3);
            j += 4;
        }
        for (; j < e; ++j) {
            int c = col[j];
            A += bf4(*(const uint2*)(xt16 + ((size_t)c << 5) + c4));
        }
        A += bf4(*(const uint2*)(xt16 + ((size_t)node << 5) + c4));
        float dv = dis[node];
        v4f o = (A + B) * dv;
        yl[loc][c4 + 0] = o.x;
        yl[loc][c4 + 1] = o.y;
        yl[loc][c4 + 2] = o.z;
        yl[loc][c4 + 3] = o.w;
    }
    __syncthreads();
    // gemm phase
    const int wave = t >> 6;
    const int lane = t & 63;
    const int mrow = ((wave >> 1) << 4) + (lane & 15);   // local row 0..31
    const int ntBase = (wave & 1) * 4;
    const int kh = (lane >> 4) * 8;
    float a[8];
    #pragma unroll
    for (int j = 0; j < 8; ++j) a[j] = yl[mrow][kh + j];
    v8s ahi, alo;
    #pragma unroll
    for (int j = 0; j < 8; ++j) {
        ushort h = f2bf(a[j]);
        ushort l = f2bf(a[j] - bf2f(h));
        ahi[j] = (short)h;
        alo[j] = (short)l;
    }
    const ushort* bh = Whi + (size_t)lane * 8;
    const ushort* bl = Wlo + (size_t)lane * 8;
    v4f acc[4];
    #pragma unroll
    for (int i = 0; i < 4; ++i) acc[i] = (v4f){0.f, 0.f, 0.f, 0.f};
    #pragma unroll
    for (int i = 0; i < 4; ++i) {
        int nt = ntBase + i;
        v8s bhi = *(const v8s*)(bh + nt * 512);
        v8s blo = *(const v8s*)(bl + nt * 512);
        acc[i] = __builtin_amdgcn_mfma_f32_16x16x32_bf16(ahi, bhi, acc[i], 0, 0, 0);
        acc[i] = __builtin_amdgcn_mfma_f32_16x16x32_bf16(ahi, blo, acc[i], 0, 0, 0);
        acc[i] = __builtin_amdgcn_mfma_f32_16x16x32_bf16(alo, bhi, acc[i], 0, 0, 0);
    }
    const int col0 = lane & 15;
    const int orow0 = blockIdx.x * 32 + ((wave >> 1) << 4) + ((lane >> 4) << 2);
    float bb[4];
    #pragma unroll
    for (int i = 0; i < 4; ++i) bb[i] = bias[(ntBase + i) * 16 + col0];
    #pragma unroll
    for (int r = 0; r < 4; ++r) {
        int orow = orow0 + r;
        if (orow < n) {
            #pragma unroll
            for (int i = 0; i < 4; ++i)
                out[(size_t)orow * 128 + (ntBase + i) * 16 + col0] = f2bf(fmaxf(acc[i][r] + bb[i], 0.f));
        }
    }
}

// ---------------- MFMA GEMM (layers 2,3): hws = dis * (h_bf16 @ W) ----------------
// R19: 32 rows/wave (2 m-tiles share each weight-fragment load). bounds (256,4).
// Stores CACHED: A-writes warm L2 for the following k_agg gather.

__global__ __launch_bounds__(256, 4) void k_gemm_bf32(const ushort* __restrict__ in,
                                                      const ushort* __restrict__ Whi,
                                                      const ushort* __restrict__ Wlo,
                                                      const float* __restrict__ dis,
                                                      ushort* __restrict__ out, int n) {
    const int wave = threadIdx.x >> 6;
    const int lane = threadIdx.x & 63;
    const int m0 = (blockIdx.x * 4 + wave) * 32;
    if (m0 >= n) return;
    int row0 = m0 + (lane & 15);
    int row1 = row0 + 16;
    if (row0 >= n) row0 = n - 1;
    if (row1 >= n) row1 = n - 1;
    const int kh = (lane >> 4) * 8;
    const ushort* rp0 = in + (size_t)row0 * 128 + kh;
    const ushort* rp1 = in + (size_t)row1 * 128 + kh;

    v4f acc0[8], acc1[8];
    #pragma unroll
    for (int t = 0; t < 8; ++t) {
        acc0[t] = (v4f){0.f, 0.f, 0.f, 0.f};
        acc1[t] = (v4f){0.f, 0.f, 0.f, 0.f};
    }

    #pragma unroll
    for (int ks = 0; ks < 4; ++ks) {
        v8s a0 = *(const v8s*)(rp0 + ks * 32);
        v8s a1 = *(const v8s*)(rp1 + ks * 32);
        const ushort* bh = Whi + (size_t)(ks * 8) * 512 + (size_t)lane * 8;
        const ushort* bl = Wlo + (size_t)(ks * 8) * 512 + (size_t)lane * 8;
        #pragma unroll
        for (int nt = 0; nt < 8; ++nt) {
            v8s bhi = *(const v8s*)(bh + nt * 512);
            v8s blo = *(const v8s*)(bl + nt * 512);
            acc0[nt] = __builtin_amdgcn_mfma_f32_16x16x32_bf16(a0, bhi, acc0[nt], 0, 0, 0);
            acc0[nt] = __builtin_amdgcn_mfma_f32_16x16x32_bf16(a0, blo, acc0[nt], 0, 0, 0);
            acc1[nt] = __builtin_amdgcn_mfma_f32_16x16x32_bf16(a1, bhi, acc1[nt], 0, 0, 0);
            acc1[nt] = __builtin_amdgcn_mfma_f32_16x16x32_bf16(a1, blo, acc1[nt], 0, 0, 0);
        }
    }

    const int col0 = lane & 15;
    const int orow0 = m0 + (lane >> 4) * 4;
    #pragma unroll
    for (int r = 0; r < 4; ++r) {
        int orow = orow0 + r;
        if (orow < n) {
            float dv = dis[orow];
            #pragma unroll
            for (int nt = 0; nt < 8; ++nt)
                out[(size_t)orow * 128 + nt * 16 + col0] = f2bf(acc0[nt][r] * dv);
        }
        int orow2 = orow + 16;
        if (orow2 < n) {
            float dv = dis[orow2];
            #pragma unroll
            for (int nt = 0; nt < 8; ++nt)
                out[(size_t)orow2 * 128 + nt * 16 + col0] = f2bf(acc1[nt][r] * dv);
        }
    }
}

// ---------------- layer-2 aggregation: channel-split, merged halves ----------------
// out[i][:] = bf16( relu( dis[i]*( sum_j hws[col[j]] + hws[i] ) + b ) )
// 8-deep/(256,6) measured local optimum (94.2us / 297 MB / 3.45 TB/s).

__global__ __launch_bounds__(256, 6) void k_agg(const ushort* __restrict__ hws, const int* __restrict__ rp,
                                                const int* __restrict__ col, const float* __restrict__ dis,
                                                const float* __restrict__ bias, ushort* __restrict__ out, int n) {
    int g = blockIdx.x * 32 + (threadIdx.x >> 3);   // group id in [0, 2n)
    int node = (g < n) ? g : g - n;                 // half0: ch 0-63, half1: ch 64-127
    if (g >= 2 * n) return;
    int c8 = ((g < n) ? 0 : 64) + ((threadIdx.x & 7) << 3);
    int s = rp[node], e = rp[node + 1];
    float A[8] = {0.f, 0.f, 0.f, 0.f, 0.f, 0.f, 0.f, 0.f};
    float B[8] = {0.f, 0.f, 0.f, 0.f, 0.f, 0.f, 0.f, 0.f};
    int j = s;
    for (; j + 7 < e; j += 8) {
        int c0 = col[j],     c1 = col[j + 1], c2 = col[j + 2], c3 = col[j + 3];
        int c4 = col[j + 4], c5 = col[j + 5], c6 = col[j + 6], c7 = col[j + 7];
        uint4 q0 = *(const uint4*)(hws + ((size_t)c0 << 7) + c8);
        uint4 q1 = *(const uint4*)(hws + ((size_t)c1 << 7) + c8);
        uint4 q2 = *(const uint4*)(hws + ((size_t)c2 << 7) + c8);
        uint4 q3 = *(const uint4*)(hws + ((size_t)c3 << 7) + c8);
        uint4 q4 = *(const uint4*)(hws + ((size_t)c4 << 7) + c8);
        uint4 q5 = *(const uint4*)(hws + ((size_t)c5 << 7) + c8);
        uint4 q6 = *(const uint4*)(hws + ((size_t)c6 << 7) + c8);
        uint4 q7 = *(const uint4*)(hws + ((size_t)c7 << 7) + c8);
        bfadd(A, q0); bfadd(B, q1); bfadd(A, q2); bfadd(B, q3);
        bfadd(A, q4); bfadd(B, q5); bfadd(A, q6); bfadd(B, q7);
    }
    if (j + 3 < e) {
        int c0 = col[j], c1 = col[j + 1], c2 = col[j + 2], c3 = col[j + 3];
        uint4 q0 = *(const uint4*)(hws + ((size_t)c0 << 7) + c8);
        uint4 q1 = *(const uint4*)(hws + ((size_t)c1 << 7) + c8);
        uint4 q2 = *(const uint4*)(hws + ((size_t)c2 << 7) + c8);
        uint4 q3 = *(const uint4*)(hws + ((size_t)c3 << 7) + c8);
        bfadd(A, q0); bfadd(B, q1); bfadd(A, q2); bfadd(B, q3);
        j += 4;
    }
    for (; j < e; ++j) {
        int c = col[j];
        uint4 q = *(const uint4*)(hws + ((size_t)c << 7) + c8);
        bfadd(A, q);
    }
    uint4 qs = *(const uint4*)(hws + ((size_t)node << 7) + c8);
    bfadd(A, qs);
    float dv = dis[node];
    float4 bv0 = *(const float4*)(bias + c8);
    float4 bv1 = *(const float4*)(bias + c8 + 4);
    float r0 = fmaxf(dv * (A[0] + B[0]) + bv0.x, 0.f);
    float r1 = fmaxf(dv * (A[1] + B[1]) + bv0.y, 0.f);
    float r2 = fmaxf(dv * (A[2] + B[2]) + bv0.z, 0.f);
    float r3 = fmaxf(dv * (A[3] + B[3]) + bv0.w, 0.f);
    float r4 = fmaxf(dv * (A[4] + B[4]) + bv1.x, 0.f);
    float r5 = fmaxf(dv * (A[5] + B[5]) + bv1.y, 0.f);
    float r6 = fmaxf(dv * (A[6] + B[6]) + bv1.z, 0.f);
    float r7 = fmaxf(dv * (A[7] + B[7]) + bv1.w, 0.f);
    uint4 o;
    o.x = pack2(r0, r1);
    o.y = pack2(r2, r3);
    o.z = pack2(r4, r5);
    o.w = pack2(r6, r7);
    *(uint4*)(out + (size_t)node * 128 + c8) = o;
}

// ---------------- layer-3 aggregation + fused mean-pool accumulation (R27) ----------------
// Layer-3 h is consumed ONLY by the pool -> never write it to HBM. Same gather
// as k_agg, but the fp32 relu outputs (pre-bf16, CLOSER to reference) are
// block-reduced in LDS (32 consecutive nodes span <=2 graphs: min graph size
// ~150 >> 32) and atomic-added into pooled[512][128]. Saves 25 MB write here
// + 25.6 MB read in pool_head. Grid exact (2N = 6250*32) -> no early returns,
// barrier-safe.

__global__ __launch_bounds__(256, 6) void k_agg_pool(const ushort* __restrict__ hws, const int* __restrict__ rp,
                                                     const int* __restrict__ col, const float* __restrict__ dis,
                                                     const float* __restrict__ bias, const int* __restrict__ batch,
                                                     float* __restrict__ pooled, int n) {
    __shared__ float red[256][8];
    __shared__ int gID[32];
    int t = threadIdx.x;
    int g = blockIdx.x * 32 + (t >> 3);             // group id in [0, 2n), grid exact
    int node = (g < n) ? g : g - n;                 // half0: ch 0-63, half1: ch 64-127
    int half = (g < n) ? 0 : 1;
    int c8 = half * 64 + ((t & 7) << 3);
    int s = rp[node], e = rp[node + 1];
    float A[8] = {0.f, 0.f, 0.f, 0.f, 0.f, 0.f, 0.f, 0.f};
    float B[8] = {0.f, 0.f, 0.f, 0.f, 0.f, 0.f, 0.f, 0.f};
    int j = s;
    for (; j + 7 < e; j += 8) {
        int c0 = col[j],     c1 = col[j + 1], c2 = col[j + 2], c3 = col[j + 3];
        int c4 = col[j + 4], c5 = col[j + 5], c6 = col[j + 6], c7 = col[j + 7];
        uint4 q0 = *(const uint4*)(hws + ((size_t)c0 << 7) + c8);
        uint4 q1 = *(const uint4*)(hws + ((size_t)c1 << 7) + c8);
        uint4 q2 = *(const uint4*)(hws + ((size_t)c2 << 7) + c8);
        uint4 q3 = *(const uint4*)(hws + ((size_t)c3 << 7) + c8);
        uint4 q4 = *(const uint4*)(hws + ((size_t)c4 << 7) + c8);
        uint4 q5 = *(const uint4*)(hws + ((size_t)c5 << 7) + c8);
        uint4 q6 = *(const uint4*)(hws + ((size_t)c6 << 7) + c8);
        uint4 q7 = *(const uint4*)(hws + ((size_t)c7 << 7) + c8);
        bfadd(A, q0); bfadd(B, q1); bfadd(A, q2); bfadd(B, q3);
        bfadd(A, q4); bfadd(B, q5); bfadd(A, q6); bfadd(B, q7);
    }
    if (j + 3 < e) {
        int c0 = col[j], c1 = col[j + 1], c2 = col[j + 2], c3 = col[j + 3];
        uint4 q0 = *(const uint4*)(hws + ((size_t)c0 << 7) + c8);
        uint4 q1 = *(const uint4*)(hws + ((size_t)c1 << 7) + c8);
        uint4 q2 = *(const uint4*)(hws + ((size_t)c2 << 7) + c8);
        uint4 q3 = *(const uint4*)(hws + ((size_t)c3 << 7) + c8);
        bfadd(A, q0); bfadd(B, q1); bfadd(A, q2); bfadd(B, q3);
        j += 4;
    }
    for (; j < e; ++j) {
        int c = col[j];
        uint4 q = *(const uint4*)(hws + ((size_t)c << 7) + c8);
        bfadd(A, q);
    }
    uint4 qs = *(const uint4*)(hws + ((size_t)node << 7) + c8);
    bfadd(A, qs);
    float dv = dis[node];
    float4 bv0 = *(const float4*)(bias + c8);
    float4 bv1 = *(const float4*)(bias + c8 + 4);
    red[t][0] = fmaxf(dv * (A[0] + B[0]) + bv0.x, 0.f);
    red[t][1] = fmaxf(dv * (A[1] + B[1]) + bv0.y, 0.f);
    red[t][2] = fmaxf(dv * (A[2] + B[2]) + bv0.z, 0.f);
    red[t][3] = fmaxf(dv * (A[3] + B[3]) + bv0.w, 0.f);
    red[t][4] = fmaxf(dv * (A[4] + B[4]) + bv1.x, 0.f);
    red[t][5] = fmaxf(dv * (A[5] + B[5]) + bv1.y, 0.f);
    red[t][6] = fmaxf(dv * (A[6] + B[6]) + bv1.z, 0.f);
    red[t][7] = fmaxf(dv * (A[7] + B[7]) + bv1.w, 0.f);
    if ((t & 7) == 0) gID[t >> 3] = batch[node];
    __syncthreads();
    if (t < 64) {
        int lane8 = t >> 3, k = t & 7;
        int g0 = gID[0], g1 = gID[31];
        float s0 = 0.f, s1 = 0.f;
        #pragma unroll 4
        for (int gr = 0; gr < 32; ++gr) {
            float v = red[(gr << 3) + lane8][k];
            if (gID[gr] == g0) s0 += v; else s1 += v;
        }
        int ch = half * 64 + (lane8 << 3) + k;
        atomicAdd(&pooled[(size_t)g0 * 128 + ch], s0);
        if (g1 != g0) atomicAdd(&pooled[(size_t)g1 * 128 + ch], s1);
    }
}

// ---------------- head: counts + divide + mu/logvar GEMM (pooling pre-done) ----------------

__global__ __launch_bounds__(256) void k_pool_head(const float* __restrict__ pooled, const int* __restrict__ batch,
                                                   const float* __restrict__ Wmu, const float* __restrict__ bmu,
                                                   const float* __restrict__ Wlv, const float* __restrict__ blv,
                                                   float* __restrict__ out, int n) {
    int g = blockIdx.x;
    int t = threadIdx.x;
    int lo = 0, hi = n;
    while (lo < hi) { int m = (lo + hi) >> 1; if (batch[m] < g) lo = m + 1; else hi = m; }
    int start = lo;
    hi = n;
    while (lo < hi) { int m = (lo + hi) >> 1; if (batch[m] < g + 1) lo = m + 1; else hi = m; }
    int end = lo;

    __shared__ float pl[128];
    float inv = 1.0f / fmaxf((float)(end - start), 1.0f);
    if (t < 128) pl[t] = pooled[(size_t)g * 128 + t] * inv;
    __syncthreads();
    float amu = bmu[t], alv = blv[t];
    for (int k = 0; k < 128; k += 4) {
        float p0 = pl[k], p1 = pl[k + 1], p2 = pl[k + 2], p3 = pl[k + 3];
        amu += p0 * Wmu[(k + 0) * 256 + t] + p1 * Wmu[(k + 1) * 256 + t]
             + p2 * Wmu[(k + 2) * 256 + t] + p3 * Wmu[(k + 3) * 256 + t];
        alv += p0 * Wlv[(k + 0) * 256 + t] + p1 * Wlv[(k + 1) * 256 + t]
             + p2 * Wlv[(k + 2) * 256 + t] + p3 * Wlv[(k + 3) * 256 + t];
    }
    out[(size_t)g * 256 + t] = amu;
    out[(size_t)N_GRAPHS * 256 + (size_t)g * 256 + t] = alv;
}

// ---------------- launch ----------------

extern "C" void kernel_launch(void* const* d_in, const int* in_sizes, int n_in,
                              void* d_out, int out_size, void* d_ws, size_t ws_size,
                              hipStream_t stream) {
    const float* x    = (const float*)d_in[0];
    const int*   eidx = (const int*)d_in[1];
    const int*   batch= (const int*)d_in[2];
    const float* W1   = (const float*)d_in[3];
    const float* b1   = (const float*)d_in[4];
    const float* W2   = (const float*)d_in[5];
    const float* b2   = (const float*)d_in[6];
    const float* W3   = (const float*)d_in[7];
    const float* b3   = (const float*)d_in[8];
    const float* Wmu  = (const float*)d_in[9];
    const float* bmu  = (const float*)d_in[10];
    const float* Wlv  = (const float*)d_in[11];
    const float* blv  = (const float*)d_in[12];
    float* out = (float*)d_out;

    const int N = N_NODES, E = N_EDGES;
    const int* srcp = eidx;
    const int* dstp = eidx + E;

    // workspace layout
    ushort* w1h = (ushort*)d_ws;            // 4096
    ushort* w1l = w1h + 4096;               // 4096
    ushort* w2h = w1l + 4096;               // 16384
    ushort* w2l = w2h + 16384;              // 16384
    ushort* w3h = w2l + 16384;              // 16384
    ushort* w3l = w3h + 16384;              // 16384
    ushort* A   = w3l + 16384;              // N*128 bf16 (hws, gathered)
    ushort* B   = A + (size_t)N * 128;      // N*128 bf16 (h)
    float*  dis = (float*)(B + (size_t)N * 128);  // N
    int*   rp   = (int*)(dis + N);          // N+1 (pad 2)
    int*   bktCnt   = rp + (N + 2);         // NB (pad 512)
    int*   colStart = bktCnt + 512;         // NB+1 (pad 512) — unused since R22
    int*   packed = colStart + 512;         // NB*CAP
    int*   col    = packed + (size_t)NB * CAP;  // E
    float* pooled = (float*)(col + (size_t)E);  // 512*128 fp32 (R27)

    // layer-1 bf16 x-tilde table aliases A (dead until k_gemm_bf32 writes it):
    // xt16 = N*32 bf16 (6.4 MB). y lives in LDS only (R22 fusion).
    ushort* xt16 = A;

    const int gE8192 = (E + 8191) / 8192;   // 391

    // W packs + bktCnt/pooled zeroing (one launch, runs before binA/agg3)
    k_pack_all<<<256, 256, 0, stream>>>(W1, W2, W3, w1h, w1l, w2h, w2l, w3h, w3l, bktCnt, pooled);

    // single-pass binned CSR build; binB folds bscan + emits bf16 xt
    k_binA<<<gE8192, 1024, 0, stream>>>(srcp, dstp, bktCnt, packed, E);
    k_binB<<<NB, 1024, 0, stream>>>(bktCnt, packed, col, rp, dis, x, xt16, N);

    const int gGemm2 = (N + 127) / 128;     // 782  (32 rows/wave)
    const int gL1    = (N + 31) / 32;       // 3125 (32 nodes/block)
    const int gAgg   = (2 * N + 31) / 32;   // 6250: both halves, one dispatch

    // layer 1: fused 29-dim agg (bf16 table) + GEMM(+bias+relu)
    k_l1<<<gL1, 256, 0, stream>>>(xt16, rp, col, dis, w1h, w1l, b1, B, N);

    // layer 2: GEMM -> agg(+bias+relu)
    k_gemm_bf32<<<gGemm2, 256, 0, stream>>>(B, w2h, w2l, dis, A, N);
    k_agg<<<gAgg, 256, 0, stream>>>(A, rp, col, dis, b2, B, N);
    // layer 3: GEMM -> agg fused with pooling (h never hits HBM)
    k_gemm_bf32<<<gGemm2, 256, 0, stream>>>(B, w3h, w3l, dis, A, N);
    k_agg_pool<<<gAgg, 256, 0, stream>>>(A, rp, col, dis, b3, batch, pooled, N);
    k_pool_head<<<N_GRAPHS, 256, 0, stream>>>(pooled, batch, Wmu, bmu, Wlv, blv, out, N);
}